// Round 16
// baseline (423.199 us; speedup 1.0000x reference)
//
#include <hip/hip_runtime.h>
#include <hip/hip_fp16.h>

constexpr int N  = 50000;
constexpr int E  = 1600000;                 // self-loops handled analytically
constexpr int NF = 128;
constexpr int BSH = 128;                    // dsts per bucket
constexpr int NB = (N + BSH - 1) / BSH;     // 391 buckets
constexpr int CAP = 8192;                   // slots per bucket (mean ~4094, sigma 64)
constexpr int EPB  = 8192;                  // edges per block (binscatter)
constexpr int NBLK = (E + EPB - 1) / EPB;   // 196
constexpr int PACKW_BLKS = (2 * NF * NF + 1023) / 1024;  // 32
constexpr int GEMM1_BLKS = (N + 127) / 128; // 391
constexpr int SCAPW = 128;                  // per-wave edge stash in aggregate
constexpr int DBINS = 256;                  // degree histogram bins

typedef _Float16 half8 __attribute__((ext_vector_type(8)));
typedef float    f32x4 __attribute__((ext_vector_type(4)));

// ---------------- fused binscatter + weight packing + w2 projections ----------------
__global__ __launch_bounds__(1024) void k_scatter_packw(
    const int* __restrict__ ei, int* __restrict__ bcur, int* __restrict__ packed,
    const float* __restrict__ W1, const float* __restrict__ W2,
    __half* __restrict__ P1, __half* __restrict__ P2,
    const float* __restrict__ as2, const float* __restrict__ ad2,
    float* __restrict__ w2as, float* __restrict__ w2ad) {
    int t = threadIdx.x;
    if (blockIdx.x == NBLK + PACKW_BLKS) {  // ---- w2 projection path ----
        if (t < NF) {
            float ps = 0.f, pd = 0.f;
            for (int j = 0; j < NF; ++j) {
                float w = W2[t * NF + j];
                ps = fmaf(w, as2[j], ps);
                pd = fmaf(w, ad2[j], pd);
            }
            w2as[t] = ps; w2ad[t] = pd;
        }
        return;
    }
    if (blockIdx.x >= NBLK) {               // ---- packw path ----
        int tid = (blockIdx.x - NBLK) * 1024 + t;
        if (tid >= 2 * NF * NF) return;
        int which = tid >> 14;
        int id = tid & (NF * NF - 1);
        int k = id >> 7, n = id & 127;
        const float* W = which ? W2 : W1;
        __half* P = which ? P2 : P1;
        int ks = k >> 5, r = k & 31, ct = n >> 4;
        int lane = ((r >> 3) << 4) | (n & 15);
        int j = r & 7;
        P[((ks * 8 + ct) * 64 + lane) * 8 + j] = __float2half_rn(W[k * NF + n]);
        return;
    }
    // ---- binscatter path (real edges only; self-loops analytic) ----
    __shared__ int h[NB], lcur[NB], garr[NB];
    for (int i = t; i < NB; i += 1024) h[i] = 0;
    __syncthreads();
    int base = blockIdx.x * EPB;
    int pk[EPB / 1024];
    int bk[EPB / 1024];
#pragma unroll
    for (int k = 0; k < EPB / 1024; ++k) {
        int i = base + k * 1024 + t;
        if (i < E) {
            int s = ei[i], d = ei[E + i];
            bk[k] = d >> 7;
            pk[k] = s | ((d & (BSH - 1)) << 16);
            atomicAdd(&h[bk[k]], 1);
        } else bk[k] = -1;
    }
    __syncthreads();
    for (int i = t; i < NB; i += 1024) {
        lcur[i] = 0;
        garr[i] = i * CAP + (h[i] ? atomicAdd(&bcur[i], h[i]) : 0);
    }
    __syncthreads();
#pragma unroll
    for (int k = 0; k < EPB / 1024; ++k) {
        if (bk[k] >= 0) {
            int p = garr[bk[k]] + atomicAdd(&lcur[bk[k]], 1);
            packed[p] = pk[k];
        }
    }
}

// ---------------- shared GEMM wave body (16 rows x 128 cols) ----------------
template <typename AT>
__device__ __forceinline__ void gemm_rows16(
    const AT* __restrict__ A, const half8* __restrict__ BP,
    const float* __restrict__ asv, const float* __restrict__ adv,
    __half* __restrict__ H16, float* __restrict__ AS, float* __restrict__ AD,
    int base, int lane) {
    int row_a = base + (lane & 15);
    if (row_a >= N) row_a = N - 1;
    const AT* Arow = A + (size_t)row_a * NF;

    f32x4 acc[8] = {};
#pragma unroll
    for (int ks = 0; ks < 4; ++ks) {
        int eo = (ks * 4 + (lane >> 4)) * 8;
        half8 a;
        if constexpr (sizeof(AT) == 4) {
            float4 u = *(const float4*)(Arow + eo);
            float4 v = *(const float4*)(Arow + eo + 4);
            a[0] = (_Float16)u.x; a[1] = (_Float16)u.y; a[2] = (_Float16)u.z; a[3] = (_Float16)u.w;
            a[4] = (_Float16)v.x; a[5] = (_Float16)v.y; a[6] = (_Float16)v.z; a[7] = (_Float16)v.w;
        } else {
            a = ((const half8*)Arow)[ks * 4 + (lane >> 4)];
        }
#pragma unroll
        for (int ct = 0; ct < 8; ++ct) {
            half8 b = BP[(ks * 8 + ct) * 64 + lane];
            acc[ct] = __builtin_amdgcn_mfma_f32_16x16x32_f16(a, b, acc[ct], 0, 0, 0);
        }
    }

    int colb = lane & 15;
    int rowq = base + (lane >> 4) * 4;
    float ps[4] = {0.f, 0.f, 0.f, 0.f};
    float pd[4] = {0.f, 0.f, 0.f, 0.f};
#pragma unroll
    for (int ct = 0; ct < 8; ++ct) {
        int col = ct * 16 + colb;
        float av = asv[col], dv = adv[col];
#pragma unroll
        for (int r = 0; r < 4; ++r) {
            float hv = acc[ct][r];
            if (rowq + r < N) H16[(size_t)(rowq + r) * NF + col] = __float2half_rn(hv);
            ps[r] = fmaf(hv, av, ps[r]);
            pd[r] = fmaf(hv, dv, pd[r]);
        }
    }
#pragma unroll
    for (int r = 0; r < 4; ++r) {
#pragma unroll
        for (int o = 1; o <= 8; o <<= 1) {
            ps[r] += __shfl_xor(ps[r], o);
            pd[r] += __shfl_xor(pd[r], o);
        }
    }
    if (colb == 0) {
#pragma unroll
        for (int r = 0; r < 4; ++r) {
            if (rowq + r < N) { AS[rowq + r] = ps[r]; AD[rowq + r] = pd[r]; }
        }
    }
}

// ---------------- fused k_csr + layer-1 GEMM (even/odd split) ----------------
// csr path also emits deg[] and a 256-bin global degree histogram.
__global__ __launch_bounds__(512) void k_csr_gemm1(
    const int* __restrict__ packed, const int* __restrict__ bcur,
    int* __restrict__ offB, int* __restrict__ offE, unsigned short* __restrict__ srcs,
    int* __restrict__ deg, int* __restrict__ dhist,
    const float* __restrict__ X, const __half* __restrict__ Wpk,
    const float* __restrict__ asv, const float* __restrict__ adv,
    __half* __restrict__ H16, float* __restrict__ AS, float* __restrict__ AD) {
    int t = threadIdx.x;
    if ((blockIdx.x & 1) == 0) {            // ---- GEMM1 path ----
        int blk = blockIdx.x >> 1;
        int wave = t >> 6, lane = t & 63;
        int base = blk * 128 + wave * 16;
        gemm_rows16<float>(X, (const half8*)Wpk, asv, adv, H16, AS, AD, base, lane);
        return;
    }
    // ---- csr path ----
    int b = blockIdx.x >> 1;
    int s0 = b * CAP;
    int n = bcur[b];
    __shared__ int buf[CAP];
    __shared__ int h[BSH], bas[BSH], lcur[BSH];
    for (int i = t; i < n; i += 512) buf[i] = packed[s0 + i];
    if (t < BSH) { h[t] = 0; lcur[t] = 0; }
    __syncthreads();
    for (int i = t; i < n; i += 512)
        atomicAdd(&h[(buf[i] >> 16) & (BSH - 1)], 1);
    __syncthreads();
    if (t < BSH) {
        int d = b * BSH + t;
        if (d < N) {
            deg[d] = h[t];
            int bin = h[t] < DBINS - 1 ? h[t] : DBINS - 1;
            atomicAdd(&dhist[bin], 1);
        }
    }
    if (t < 64) {                           // one wave scans 128 bins, 2 per lane
        int v0 = h[2 * t], v1 = h[2 * t + 1];
        int pair = v0 + v1, x = pair;
#pragma unroll
        for (int o = 1; o < 64; o <<= 1) {
            int y = __shfl_up(x, o);
            if (t >= o) x += y;
        }
        int e0 = s0 + x - pair;
        int e1 = e0 + v0;
        bas[2 * t] = e0; bas[2 * t + 1] = e1;
        int d = b * BSH + 2 * t;
        if (d < N)     { offB[d] = e0;     offE[d] = e1; }
        if (d + 1 < N) { offB[d + 1] = e1; offE[d + 1] = s0 + x; }
    }
    __syncthreads();
    for (int i = t; i < n; i += 512) {
        int p = buf[i];
        int dl = (p >> 16) & (BSH - 1);
        int pos = bas[dl] + atomicAdd(&lcur[dl], 1);
        srcs[pos] = (unsigned short)(p & 0xFFFF);
    }
}

// ---------------- degree-sorted permutation scatter ----------------
// each block redundantly scans the 256-bin histogram in LDS, then scatters.
__global__ __launch_bounds__(256) void k_permscatter(
    const int* __restrict__ deg, const int* __restrict__ dhist,
    int* __restrict__ dcnt, int* __restrict__ perm) {
    __shared__ int sc[DBINS];
    int t = threadIdx.x;
    int v = dhist[t];
    sc[t] = v;
    __syncthreads();
    for (int o = 1; o < DBINS; o <<= 1) {
        int a = (t >= o) ? sc[t - o] : 0;
        __syncthreads();
        sc[t] += a;
        __syncthreads();
    }
    int d = blockIdx.x * 256 + t;
    if (d >= N) return;
    int dg = deg[d];
    int bin = dg < DBINS - 1 ? dg : DBINS - 1;
    int base = sc[bin] - dhist[bin];        // exclusive base of bin
    int pos = base + atomicAdd(&dcnt[bin], 1);
    perm[pos] = d;
}

// ---------------- aggregate-1 fused with layer-2 GEMM (degree-sorted dsts) ----------------
__global__ __launch_bounds__(1024) void k_agg1_gemm2(
    const __half* __restrict__ H16in, const float* __restrict__ AS, const float* __restrict__ AD,
    const int* __restrict__ offB, const int* __restrict__ offE,
    const unsigned short* __restrict__ srcs, const int* __restrict__ perm,
    const float* __restrict__ b1, const __half* __restrict__ Wpk2,
    const float* __restrict__ w2as, const float* __restrict__ w2ad,
    __half* __restrict__ H16out, float* __restrict__ AS2, float* __restrict__ AD2) {
    int wave = threadIdx.x >> 6, lane = threadIdx.x & 63;
    int d = perm[blockIdx.x * 16 + wave];   // N % 16 == 0

    __shared__ float ssv[16][SCAPW];
    __shared__ unsigned short ssrc[16][SCAPW];
    __shared__ __half Y[16][136];
    __shared__ int dd[16];
    if (lane == 0) dd[wave] = d;

    int beg = offB[d], deg = offE[d] - beg;
    float ad = AD[d];

    // pass 1: one exp per edge, stash, wave-reduce denominator
    float ls = 0.f;
    for (int i = lane; i < deg; i += 64) {
        int s = srcs[beg + i];
        float sv = AS[s] + ad;
        sv = (sv > 0.f) ? sv : 0.2f * sv;
        float e = __expf(fminf(sv, 60.f));
        if (i < SCAPW) { ssv[wave][i] = e; ssrc[wave][i] = (unsigned short)s; }
        ls += e;
    }
#pragma unroll
    for (int o = 1; o <= 32; o <<= 1) ls += __shfl_xor(ls, o);
    // analytic self-loop
    float slv = AS[d] + ad;
    slv = (slv > 0.f) ? slv : 0.2f * slv;
    float es = __expf(fminf(slv, 60.f));
    ls += es;
    float inv = 1.f / (ls + 1e-16f);

    // pass 2: gather-accumulate, 2x unrolled
    int tx = lane & 15, u = lane >> 4;
    float acc[8] = {0.f, 0.f, 0.f, 0.f, 0.f, 0.f, 0.f, 0.f};
    for (int j0 = 0; j0 < deg; j0 += 8) {
        int i0 = j0 + u, i1 = j0 + 4 + u;
        float e0 = 0.f, e1 = 0.f;
        int s0 = 0, s1 = 0;
        bool v0 = i0 < deg, v1 = i1 < deg;
        if (v0) {
            if (i0 < SCAPW) { e0 = ssv[wave][i0]; s0 = ssrc[wave][i0]; }
            else {
                s0 = srcs[beg + i0];
                float sv = AS[s0] + ad;
                sv = (sv > 0.f) ? sv : 0.2f * sv;
                e0 = __expf(fminf(sv, 60.f));
            }
        }
        if (v1) {
            if (i1 < SCAPW) { e1 = ssv[wave][i1]; s1 = ssrc[wave][i1]; }
            else {
                s1 = srcs[beg + i1];
                float sv = AS[s1] + ad;
                sv = (sv > 0.f) ? sv : 0.2f * sv;
                e1 = __expf(fminf(sv, 60.f));
            }
        }
        union { float4 f; __half2 h[4]; } va, vb;
        if (v0) va.f = *reinterpret_cast<const float4*>(H16in + (size_t)s0 * NF + tx * 8);
        if (v1) vb.f = *reinterpret_cast<const float4*>(H16in + (size_t)s1 * NF + tx * 8);
        if (v0) {
            float2 f0 = __half22float2(va.h[0]);
            float2 f1 = __half22float2(va.h[1]);
            float2 f2 = __half22float2(va.h[2]);
            float2 f3 = __half22float2(va.h[3]);
            acc[0] = fmaf(e0, f0.x, acc[0]); acc[1] = fmaf(e0, f0.y, acc[1]);
            acc[2] = fmaf(e0, f1.x, acc[2]); acc[3] = fmaf(e0, f1.y, acc[3]);
            acc[4] = fmaf(e0, f2.x, acc[4]); acc[5] = fmaf(e0, f2.y, acc[5]);
            acc[6] = fmaf(e0, f3.x, acc[6]); acc[7] = fmaf(e0, f3.y, acc[7]);
        }
        if (v1) {
            float2 f0 = __half22float2(vb.h[0]);
            float2 f1 = __half22float2(vb.h[1]);
            float2 f2 = __half22float2(vb.h[2]);
            float2 f3 = __half22float2(vb.h[3]);
            acc[0] = fmaf(e1, f0.x, acc[0]); acc[1] = fmaf(e1, f0.y, acc[1]);
            acc[2] = fmaf(e1, f1.x, acc[2]); acc[3] = fmaf(e1, f1.y, acc[3]);
            acc[4] = fmaf(e1, f2.x, acc[4]); acc[5] = fmaf(e1, f2.y, acc[5]);
            acc[6] = fmaf(e1, f3.x, acc[6]); acc[7] = fmaf(e1, f3.y, acc[7]);
        }
    }
#pragma unroll
    for (int o = 16; o <= 32; o <<= 1) {
#pragma unroll
        for (int i = 0; i < 8; ++i) acc[i] += __shfl_xor(acc[i], o);
    }
    // self contribution
    {
        union { float4 f; __half2 h[4]; } vs;
        vs.f = *reinterpret_cast<const float4*>(H16in + (size_t)d * NF + tx * 8);
        float2 f0 = __half22float2(vs.h[0]);
        float2 f1 = __half22float2(vs.h[1]);
        float2 f2 = __half22float2(vs.h[2]);
        float2 f3 = __half22float2(vs.h[3]);
        acc[0] = fmaf(es, f0.x, acc[0]); acc[1] = fmaf(es, f0.y, acc[1]);
        acc[2] = fmaf(es, f1.x, acc[2]); acc[3] = fmaf(es, f1.y, acc[3]);
        acc[4] = fmaf(es, f2.x, acc[4]); acc[5] = fmaf(es, f2.y, acc[5]);
        acc[6] = fmaf(es, f3.x, acc[6]); acc[7] = fmaf(es, f3.y, acc[7]);
    }
    // epilogue math: y = leaky(acc*inv + b1); alpha-2 via precomputed projections
    float y[8];
    float ps = 0.f, pd = 0.f;
#pragma unroll
    for (int i = 0; i < 8; ++i) {
        float v = acc[i] * inv + b1[tx * 8 + i];
        v = (v < 0.f) ? 0.01f * v : v;
        y[i] = v;
        ps = fmaf(v, w2as[tx * 8 + i], ps);
        pd = fmaf(v, w2ad[tx * 8 + i], pd);
    }
#pragma unroll
    for (int o = 1; o <= 8; o <<= 1) { ps += __shfl_xor(ps, o); pd += __shfl_xor(pd, o); }
    if (lane == 0) { AS2[d] = ps; AD2[d] = pd; }
    if (lane < 16) {
        half8 hv;
#pragma unroll
        for (int i = 0; i < 8; ++i) hv[i] = (_Float16)y[i];
        *(half8*)(&Y[wave][tx * 8]) = hv;
    }
    __syncthreads();
    // epilogue GEMM: waves 0-7 each compute one 16-col tile of Y(16x128)@W2
    if (wave < 8) {
        const half8* BP = (const half8*)Wpk2;
        f32x4 c4 = {};
#pragma unroll
        for (int ks = 0; ks < 4; ++ks) {
            half8 a = *(const half8*)(&Y[lane & 15][ks * 32 + (lane >> 4) * 8]);
            half8 b = BP[(ks * 8 + wave) * 64 + lane];
            c4 = __builtin_amdgcn_mfma_f32_16x16x32_f16(a, b, c4, 0, 0, 0);
        }
        int colb = lane & 15;
        int rowq = (lane >> 4) * 4;
#pragma unroll
        for (int r = 0; r < 4; ++r)
            H16out[(size_t)dd[rowq + r] * NF + wave * 16 + colb] = __float2half_rn(c4[r]);
    }
}

// ---------------- layer-2 aggregate (wave-per-dst, degree-sorted, fp32 out) ----------------
__global__ __launch_bounds__(256) void k_aggregate2(
    const __half* __restrict__ H16, const float* __restrict__ AS, const float* __restrict__ AD,
    const int* __restrict__ offB, const int* __restrict__ offE,
    const unsigned short* __restrict__ srcs, const int* __restrict__ perm,
    const float* __restrict__ bias, float* __restrict__ OUT) {
    int wave = threadIdx.x >> 6, lane = threadIdx.x & 63;
    int d = perm[blockIdx.x * 4 + wave];

    __shared__ float ssv[4][SCAPW];
    __shared__ unsigned short ssrc[4][SCAPW];

    int beg = offB[d], deg = offE[d] - beg;
    float ad = AD[d];

    float ls = 0.f;
    for (int i = lane; i < deg; i += 64) {
        int s = srcs[beg + i];
        float sv = AS[s] + ad;
        sv = (sv > 0.f) ? sv : 0.2f * sv;
        float e = __expf(fminf(sv, 60.f));
        if (i < SCAPW) { ssv[wave][i] = e; ssrc[wave][i] = (unsigned short)s; }
        ls += e;
    }
#pragma unroll
    for (int o = 1; o <= 32; o <<= 1) ls += __shfl_xor(ls, o);
    float slv = AS[d] + ad;
    slv = (slv > 0.f) ? slv : 0.2f * slv;
    float es = __expf(fminf(slv, 60.f));
    ls += es;
    float inv = 1.f / (ls + 1e-16f);

    int tx = lane & 15, u = lane >> 4;
    float acc[8] = {0.f, 0.f, 0.f, 0.f, 0.f, 0.f, 0.f, 0.f};
    for (int j0 = 0; j0 < deg; j0 += 8) {
        int i0 = j0 + u, i1 = j0 + 4 + u;
        float e0 = 0.f, e1 = 0.f;
        int s0 = 0, s1 = 0;
        bool v0 = i0 < deg, v1 = i1 < deg;
        if (v0) {
            if (i0 < SCAPW) { e0 = ssv[wave][i0]; s0 = ssrc[wave][i0]; }
            else {
                s0 = srcs[beg + i0];
                float sv = AS[s0] + ad;
                sv = (sv > 0.f) ? sv : 0.2f * sv;
                e0 = __expf(fminf(sv, 60.f));
            }
        }
        if (v1) {
            if (i1 < SCAPW) { e1 = ssv[wave][i1]; s1 = ssrc[wave][i1]; }
            else {
                s1 = srcs[beg + i1];
                float sv = AS[s1] + ad;
                sv = (sv > 0.f) ? sv : 0.2f * sv;
                e1 = __expf(fminf(sv, 60.f));
            }
        }
        union { float4 f; __half2 h[4]; } va, vb;
        if (v0) va.f = *reinterpret_cast<const float4*>(H16 + (size_t)s0 * NF + tx * 8);
        if (v1) vb.f = *reinterpret_cast<const float4*>(H16 + (size_t)s1 * NF + tx * 8);
        if (v0) {
            float2 f0 = __half22float2(va.h[0]);
            float2 f1 = __half22float2(va.h[1]);
            float2 f2 = __half22float2(va.h[2]);
            float2 f3 = __half22float2(va.h[3]);
            acc[0] = fmaf(e0, f0.x, acc[0]); acc[1] = fmaf(e0, f0.y, acc[1]);
            acc[2] = fmaf(e0, f1.x, acc[2]); acc[3] = fmaf(e0, f1.y, acc[3]);
            acc[4] = fmaf(e0, f2.x, acc[4]); acc[5] = fmaf(e0, f2.y, acc[5]);
            acc[6] = fmaf(e0, f3.x, acc[6]); acc[7] = fmaf(e0, f3.y, acc[7]);
        }
        if (v1) {
            float2 f0 = __half22float2(vb.h[0]);
            float2 f1 = __half22float2(vb.h[1]);
            float2 f2 = __half22float2(vb.h[2]);
            float2 f3 = __half22float2(vb.h[3]);
            acc[0] = fmaf(e1, f0.x, acc[0]); acc[1] = fmaf(e1, f0.y, acc[1]);
            acc[2] = fmaf(e1, f1.x, acc[2]); acc[3] = fmaf(e1, f1.y, acc[3]);
            acc[4] = fmaf(e1, f2.x, acc[4]); acc[5] = fmaf(e1, f2.y, acc[5]);
            acc[6] = fmaf(e1, f3.x, acc[6]); acc[7] = fmaf(e1, f3.y, acc[7]);
        }
    }
#pragma unroll
    for (int o = 16; o <= 32; o <<= 1) {
#pragma unroll
        for (int i = 0; i < 8; ++i) acc[i] += __shfl_xor(acc[i], o);
    }
    {
        union { float4 f; __half2 h[4]; } vs;
        vs.f = *reinterpret_cast<const float4*>(H16 + (size_t)d * NF + tx * 8);
        float2 f0 = __half22float2(vs.h[0]);
        float2 f1 = __half22float2(vs.h[1]);
        float2 f2 = __half22float2(vs.h[2]);
        float2 f3 = __half22float2(vs.h[3]);
        acc[0] = fmaf(es, f0.x, acc[0]); acc[1] = fmaf(es, f0.y, acc[1]);
        acc[2] = fmaf(es, f1.x, acc[2]); acc[3] = fmaf(es, f1.y, acc[3]);
        acc[4] = fmaf(es, f2.x, acc[4]); acc[5] = fmaf(es, f2.y, acc[5]);
        acc[6] = fmaf(es, f3.x, acc[6]); acc[7] = fmaf(es, f3.y, acc[7]);
    }
    if (lane < 16) {
        float o8[8];
#pragma unroll
        for (int i = 0; i < 8; ++i) o8[i] = acc[i] * inv + bias[tx * 8 + i];
        float4 w0 = {o8[0], o8[1], o8[2], o8[3]};
        float4 w1 = {o8[4], o8[5], o8[6], o8[7]};
        ((float4*)OUT)[(size_t)d * 32 + tx * 2]     = w0;
        ((float4*)OUT)[(size_t)d * 32 + tx * 2 + 1] = w1;
    }
}

extern "C" void kernel_launch(void* const* d_in, const int* in_sizes, int n_in,
                              void* d_out, int out_size, void* d_ws, size_t ws_size,
                              hipStream_t stream) {
    const float* x   = (const float*)d_in[0];
    const int*   ei  = (const int*)d_in[1];
    const float* W1  = (const float*)d_in[2];
    const float* as1 = (const float*)d_in[3];
    const float* ad1 = (const float*)d_in[4];
    const float* b1  = (const float*)d_in[5];
    const float* W2  = (const float*)d_in[6];
    const float* as2 = (const float*)d_in[7];
    const float* ad2 = (const float*)d_in[8];
    const float* b2  = (const float*)d_in[9];
    float* out = (float*)d_out;

    char* p = (char*)d_ws;
    auto alloc = [&](size_t bytes) { char* r = p; p += (bytes + 255) & ~size_t(255); return (void*)r; };
    int* zreg  = (int*)alloc(sizeof(int) * (NB + 2 * DBINS));  // bcur | dhist | dcnt (one memset)
    int* bcur  = zreg;
    int* dhist = zreg + NB;
    int* dcnt  = zreg + NB + DBINS;
    int* offB  = (int*)alloc(sizeof(int) * N);
    int* offE  = (int*)alloc(sizeof(int) * N);
    int* deg   = (int*)alloc(sizeof(int) * N);
    int* perm  = (int*)alloc(sizeof(int) * N);
    unsigned short* srcs = (unsigned short*)alloc(sizeof(unsigned short) * (size_t)NB * CAP);
    __half* H16a  = (__half*)alloc(sizeof(__half) * (size_t)N * NF);
    __half* H16b  = (__half*)alloc(sizeof(__half) * (size_t)N * NF);
    __half* Wpk1  = (__half*)alloc(sizeof(__half) * NF * NF);
    __half* Wpk2  = (__half*)alloc(sizeof(__half) * NF * NF);
    float* AS1 = (float*)alloc(sizeof(float) * N);
    float* AD1 = (float*)alloc(sizeof(float) * N);
    float* AS2 = (float*)alloc(sizeof(float) * N);
    float* AD2 = (float*)alloc(sizeof(float) * N);
    float* w2as = (float*)alloc(sizeof(float) * NF);
    float* w2ad = (float*)alloc(sizeof(float) * NF);
    int* packed = (int*)alloc(sizeof(int) * (size_t)NB * CAP);

    hipMemsetAsync(zreg, 0, sizeof(int) * (NB + 2 * DBINS), stream);
    k_scatter_packw<<<NBLK + PACKW_BLKS + 1, 1024, 0, stream>>>(
        ei, bcur, packed, W1, W2, Wpk1, Wpk2, as2, ad2, w2as, w2ad);
    k_csr_gemm1<<<2 * GEMM1_BLKS, 512, 0, stream>>>(packed, bcur, offB, offE, srcs,
                                                    deg, dhist,
                                                    x, Wpk1, as1, ad1, H16a, AS1, AD1);
    k_permscatter<<<(N + 255) / 256, 256, 0, stream>>>(deg, dhist, dcnt, perm);
    k_agg1_gemm2<<<N / 16, 1024, 0, stream>>>(H16a, AS1, AD1, offB, offE, srcs, perm,
                                              b1, Wpk2, w2as, w2ad, H16b, AS2, AD2);
    k_aggregate2<<<N / 4, 256, 0, stream>>>(H16b, AS2, AD2, offB, offE, srcs, perm, b2, out);
}

// Round 17
// 191.329 us; speedup vs baseline: 2.2119x; 2.2119x over previous
//
#include <hip/hip_runtime.h>
#include <hip/hip_fp16.h>

constexpr int N  = 50000;
constexpr int E  = 1600000;                 // self-loops handled analytically
constexpr int NF = 128;
constexpr int BSH = 128;                    // dsts per bucket
constexpr int NB = (N + BSH - 1) / BSH;     // 391 buckets
constexpr int CAP = 8192;                   // slots per bucket (mean ~4094, sigma 64)
constexpr int EPB  = 8192;                  // edges per block (binscatter)
constexpr int NBLK = (E + EPB - 1) / EPB;   // 196
constexpr int PACKW_BLKS = (2 * NF * NF + 1023) / 1024;  // 32
constexpr int GEMM1_BLKS = (N + 127) / 128; // 391
constexpr int SCAPW = 128;                  // per-wave edge stash in aggregate

typedef _Float16 half8 __attribute__((ext_vector_type(8)));
typedef float    f32x4 __attribute__((ext_vector_type(4)));

// ---------------- fused binscatter + weight packing + w2 projections ----------------
__global__ __launch_bounds__(1024) void k_scatter_packw(
    const int* __restrict__ ei, int* __restrict__ bcur, int* __restrict__ packed,
    const float* __restrict__ W1, const float* __restrict__ W2,
    __half* __restrict__ P1, __half* __restrict__ P2,
    const float* __restrict__ as2, const float* __restrict__ ad2,
    float* __restrict__ w2as, float* __restrict__ w2ad) {
    int t = threadIdx.x;
    if (blockIdx.x == NBLK + PACKW_BLKS) {  // ---- w2 projection path ----
        if (t < NF) {
            float ps = 0.f, pd = 0.f;
            for (int j = 0; j < NF; ++j) {
                float w = W2[t * NF + j];
                ps = fmaf(w, as2[j], ps);
                pd = fmaf(w, ad2[j], pd);
            }
            w2as[t] = ps; w2ad[t] = pd;
        }
        return;
    }
    if (blockIdx.x >= NBLK) {               // ---- packw path ----
        int tid = (blockIdx.x - NBLK) * 1024 + t;
        if (tid >= 2 * NF * NF) return;
        int which = tid >> 14;
        int id = tid & (NF * NF - 1);
        int k = id >> 7, n = id & 127;
        const float* W = which ? W2 : W1;
        __half* P = which ? P2 : P1;
        int ks = k >> 5, r = k & 31, ct = n >> 4;
        int lane = ((r >> 3) << 4) | (n & 15);
        int j = r & 7;
        P[((ks * 8 + ct) * 64 + lane) * 8 + j] = __float2half_rn(W[k * NF + n]);
        return;
    }
    // ---- binscatter path (real edges only; self-loops analytic) ----
    __shared__ int h[NB], lcur[NB], garr[NB];
    for (int i = t; i < NB; i += 1024) h[i] = 0;
    __syncthreads();
    int base = blockIdx.x * EPB;
    int pk[EPB / 1024];
    int bk[EPB / 1024];
#pragma unroll
    for (int k = 0; k < EPB / 1024; ++k) {
        int i = base + k * 1024 + t;
        if (i < E) {
            int s = ei[i], d = ei[E + i];
            bk[k] = d >> 7;
            pk[k] = s | ((d & (BSH - 1)) << 16);
            atomicAdd(&h[bk[k]], 1);
        } else bk[k] = -1;
    }
    __syncthreads();
    for (int i = t; i < NB; i += 1024) {
        lcur[i] = 0;
        garr[i] = i * CAP + (h[i] ? atomicAdd(&bcur[i], h[i]) : 0);
    }
    __syncthreads();
#pragma unroll
    for (int k = 0; k < EPB / 1024; ++k) {
        if (bk[k] >= 0) {
            int p = garr[bk[k]] + atomicAdd(&lcur[bk[k]], 1);
            packed[p] = pk[k];
        }
    }
}

// ---------------- shared GEMM wave body (16 rows x 128 cols) ----------------
template <typename AT>
__device__ __forceinline__ void gemm_rows16(
    const AT* __restrict__ A, const half8* __restrict__ BP,
    const float* __restrict__ asv, const float* __restrict__ adv,
    __half* __restrict__ H16, float* __restrict__ AS, float* __restrict__ AD,
    int base, int lane) {
    int row_a = base + (lane & 15);
    if (row_a >= N) row_a = N - 1;
    const AT* Arow = A + (size_t)row_a * NF;

    f32x4 acc[8] = {};
#pragma unroll
    for (int ks = 0; ks < 4; ++ks) {
        int eo = (ks * 4 + (lane >> 4)) * 8;
        half8 a;
        if constexpr (sizeof(AT) == 4) {
            float4 u = *(const float4*)(Arow + eo);
            float4 v = *(const float4*)(Arow + eo + 4);
            a[0] = (_Float16)u.x; a[1] = (_Float16)u.y; a[2] = (_Float16)u.z; a[3] = (_Float16)u.w;
            a[4] = (_Float16)v.x; a[5] = (_Float16)v.y; a[6] = (_Float16)v.z; a[7] = (_Float16)v.w;
        } else {
            a = ((const half8*)Arow)[ks * 4 + (lane >> 4)];
        }
#pragma unroll
        for (int ct = 0; ct < 8; ++ct) {
            half8 b = BP[(ks * 8 + ct) * 64 + lane];
            acc[ct] = __builtin_amdgcn_mfma_f32_16x16x32_f16(a, b, acc[ct], 0, 0, 0);
        }
    }

    int colb = lane & 15;
    int rowq = base + (lane >> 4) * 4;
    float ps[4] = {0.f, 0.f, 0.f, 0.f};
    float pd[4] = {0.f, 0.f, 0.f, 0.f};
#pragma unroll
    for (int ct = 0; ct < 8; ++ct) {
        int col = ct * 16 + colb;
        float av = asv[col], dv = adv[col];
#pragma unroll
        for (int r = 0; r < 4; ++r) {
            float hv = acc[ct][r];
            if (rowq + r < N) H16[(size_t)(rowq + r) * NF + col] = __float2half_rn(hv);
            ps[r] = fmaf(hv, av, ps[r]);
            pd[r] = fmaf(hv, dv, pd[r]);
        }
    }
#pragma unroll
    for (int r = 0; r < 4; ++r) {
#pragma unroll
        for (int o = 1; o <= 8; o <<= 1) {
            ps[r] += __shfl_xor(ps[r], o);
            pd[r] += __shfl_xor(pd[r], o);
        }
    }
    if (colb == 0) {
#pragma unroll
        for (int r = 0; r < 4; ++r) {
            if (rowq + r < N) { AS[rowq + r] = ps[r]; AD[rowq + r] = pd[r]; }
        }
    }
}

// ---------------- fused k_csr + layer-1 GEMM (even/odd split) ----------------
// csr path also builds the bucket-local degree-rank permutation (NO atomics).
__global__ __launch_bounds__(512) void k_csr_gemm1(
    const int* __restrict__ packed, const int* __restrict__ bcur,
    int* __restrict__ offB, int* __restrict__ offE, unsigned short* __restrict__ srcs,
    int* __restrict__ perm,
    const float* __restrict__ X, const __half* __restrict__ Wpk,
    const float* __restrict__ asv, const float* __restrict__ adv,
    __half* __restrict__ H16, float* __restrict__ AS, float* __restrict__ AD) {
    int t = threadIdx.x;
    if ((blockIdx.x & 1) == 0) {            // ---- GEMM1 path ----
        int blk = blockIdx.x >> 1;
        int wave = t >> 6, lane = t & 63;
        int base = blk * 128 + wave * 16;
        gemm_rows16<float>(X, (const half8*)Wpk, asv, adv, H16, AS, AD, base, lane);
        return;
    }
    // ---- csr path ----
    int b = blockIdx.x >> 1;
    int s0 = b * CAP;
    int n = bcur[b];
    __shared__ int buf[CAP];
    __shared__ int h[BSH], bas[BSH], lcur[BSH];
    for (int i = t; i < n; i += 512) buf[i] = packed[s0 + i];
    if (t < BSH) { h[t] = 0; lcur[t] = 0; }
    __syncthreads();
    for (int i = t; i < n; i += 512)
        atomicAdd(&h[(buf[i] >> 16) & (BSH - 1)], 1);
    __syncthreads();
    // bucket-local degree-rank permutation (O(128) LDS scan per dst, no atomics)
    if (t < BSH) {
        int d = b * BSH + t;
        if (d < N) {
            int mydeg = h[t];
            int rank = 0;
            for (int j = 0; j < BSH; ++j) {
                if (b * BSH + j < N) {
                    int hj = h[j];
                    rank += (hj < mydeg) || (hj == mydeg && j < t);
                }
            }
            perm[b * BSH + rank] = d;
        }
    }
    if (t < 64) {                           // one wave scans 128 bins, 2 per lane
        int v0 = h[2 * t], v1 = h[2 * t + 1];
        int pair = v0 + v1, x = pair;
#pragma unroll
        for (int o = 1; o < 64; o <<= 1) {
            int y = __shfl_up(x, o);
            if (t >= o) x += y;
        }
        int e0 = s0 + x - pair;
        int e1 = e0 + v0;
        bas[2 * t] = e0; bas[2 * t + 1] = e1;
        int d = b * BSH + 2 * t;
        if (d < N)     { offB[d] = e0;     offE[d] = e1; }
        if (d + 1 < N) { offB[d + 1] = e1; offE[d + 1] = s0 + x; }
    }
    __syncthreads();
    for (int i = t; i < n; i += 512) {
        int p = buf[i];
        int dl = (p >> 16) & (BSH - 1);
        int pos = bas[dl] + atomicAdd(&lcur[dl], 1);
        srcs[pos] = (unsigned short)(p & 0xFFFF);
    }
}

// ---------------- aggregate-1 fused with layer-2 GEMM (degree-ranked dsts) ----------------
__global__ __launch_bounds__(1024) void k_agg1_gemm2(
    const __half* __restrict__ H16in, const float* __restrict__ AS, const float* __restrict__ AD,
    const int* __restrict__ offB, const int* __restrict__ offE,
    const unsigned short* __restrict__ srcs, const int* __restrict__ perm,
    const float* __restrict__ b1, const __half* __restrict__ Wpk2,
    const float* __restrict__ w2as, const float* __restrict__ w2ad,
    __half* __restrict__ H16out, float* __restrict__ AS2, float* __restrict__ AD2) {
    int wave = threadIdx.x >> 6, lane = threadIdx.x & 63;
    int d = perm[blockIdx.x * 16 + wave];   // N % 16 == 0

    __shared__ float ssv[16][SCAPW];
    __shared__ unsigned short ssrc[16][SCAPW];
    __shared__ __half Y[16][136];
    __shared__ int dd[16];
    if (lane == 0) dd[wave] = d;

    int beg = offB[d], deg = offE[d] - beg;
    float ad = AD[d];

    // pass 1: one exp per edge, stash, wave-reduce denominator
    float ls = 0.f;
    for (int i = lane; i < deg; i += 64) {
        int s = srcs[beg + i];
        float sv = AS[s] + ad;
        sv = (sv > 0.f) ? sv : 0.2f * sv;
        float e = __expf(fminf(sv, 60.f));
        if (i < SCAPW) { ssv[wave][i] = e; ssrc[wave][i] = (unsigned short)s; }
        ls += e;
    }
#pragma unroll
    for (int o = 1; o <= 32; o <<= 1) ls += __shfl_xor(ls, o);
    // analytic self-loop
    float slv = AS[d] + ad;
    slv = (slv > 0.f) ? slv : 0.2f * slv;
    float es = __expf(fminf(slv, 60.f));
    ls += es;
    float inv = 1.f / (ls + 1e-16f);

    // pass 2: gather-accumulate, 2x unrolled
    int tx = lane & 15, u = lane >> 4;
    float acc[8] = {0.f, 0.f, 0.f, 0.f, 0.f, 0.f, 0.f, 0.f};
    for (int j0 = 0; j0 < deg; j0 += 8) {
        int i0 = j0 + u, i1 = j0 + 4 + u;
        float e0 = 0.f, e1 = 0.f;
        int s0 = 0, s1 = 0;
        bool v0 = i0 < deg, v1 = i1 < deg;
        if (v0) {
            if (i0 < SCAPW) { e0 = ssv[wave][i0]; s0 = ssrc[wave][i0]; }
            else {
                s0 = srcs[beg + i0];
                float sv = AS[s0] + ad;
                sv = (sv > 0.f) ? sv : 0.2f * sv;
                e0 = __expf(fminf(sv, 60.f));
            }
        }
        if (v1) {
            if (i1 < SCAPW) { e1 = ssv[wave][i1]; s1 = ssrc[wave][i1]; }
            else {
                s1 = srcs[beg + i1];
                float sv = AS[s1] + ad;
                sv = (sv > 0.f) ? sv : 0.2f * sv;
                e1 = __expf(fminf(sv, 60.f));
            }
        }
        union { float4 f; __half2 h[4]; } va, vb;
        if (v0) va.f = *reinterpret_cast<const float4*>(H16in + (size_t)s0 * NF + tx * 8);
        if (v1) vb.f = *reinterpret_cast<const float4*>(H16in + (size_t)s1 * NF + tx * 8);
        if (v0) {
            float2 f0 = __half22float2(va.h[0]);
            float2 f1 = __half22float2(va.h[1]);
            float2 f2 = __half22float2(va.h[2]);
            float2 f3 = __half22float2(va.h[3]);
            acc[0] = fmaf(e0, f0.x, acc[0]); acc[1] = fmaf(e0, f0.y, acc[1]);
            acc[2] = fmaf(e0, f1.x, acc[2]); acc[3] = fmaf(e0, f1.y, acc[3]);
            acc[4] = fmaf(e0, f2.x, acc[4]); acc[5] = fmaf(e0, f2.y, acc[5]);
            acc[6] = fmaf(e0, f3.x, acc[6]); acc[7] = fmaf(e0, f3.y, acc[7]);
        }
        if (v1) {
            float2 f0 = __half22float2(vb.h[0]);
            float2 f1 = __half22float2(vb.h[1]);
            float2 f2 = __half22float2(vb.h[2]);
            float2 f3 = __half22float2(vb.h[3]);
            acc[0] = fmaf(e1, f0.x, acc[0]); acc[1] = fmaf(e1, f0.y, acc[1]);
            acc[2] = fmaf(e1, f1.x, acc[2]); acc[3] = fmaf(e1, f1.y, acc[3]);
            acc[4] = fmaf(e1, f2.x, acc[4]); acc[5] = fmaf(e1, f2.y, acc[5]);
            acc[6] = fmaf(e1, f3.x, acc[6]); acc[7] = fmaf(e1, f3.y, acc[7]);
        }
    }
#pragma unroll
    for (int o = 16; o <= 32; o <<= 1) {
#pragma unroll
        for (int i = 0; i < 8; ++i) acc[i] += __shfl_xor(acc[i], o);
    }
    // self contribution
    {
        union { float4 f; __half2 h[4]; } vs;
        vs.f = *reinterpret_cast<const float4*>(H16in + (size_t)d * NF + tx * 8);
        float2 f0 = __half22float2(vs.h[0]);
        float2 f1 = __half22float2(vs.h[1]);
        float2 f2 = __half22float2(vs.h[2]);
        float2 f3 = __half22float2(vs.h[3]);
        acc[0] = fmaf(es, f0.x, acc[0]); acc[1] = fmaf(es, f0.y, acc[1]);
        acc[2] = fmaf(es, f1.x, acc[2]); acc[3] = fmaf(es, f1.y, acc[3]);
        acc[4] = fmaf(es, f2.x, acc[4]); acc[5] = fmaf(es, f2.y, acc[5]);
        acc[6] = fmaf(es, f3.x, acc[6]); acc[7] = fmaf(es, f3.y, acc[7]);
    }
    // epilogue math: y = leaky(acc*inv + b1); alpha-2 via precomputed projections
    float y[8];
    float ps = 0.f, pd = 0.f;
#pragma unroll
    for (int i = 0; i < 8; ++i) {
        float v = acc[i] * inv + b1[tx * 8 + i];
        v = (v < 0.f) ? 0.01f * v : v;
        y[i] = v;
        ps = fmaf(v, w2as[tx * 8 + i], ps);
        pd = fmaf(v, w2ad[tx * 8 + i], pd);
    }
#pragma unroll
    for (int o = 1; o <= 8; o <<= 1) { ps += __shfl_xor(ps, o); pd += __shfl_xor(pd, o); }
    if (lane == 0) { AS2[d] = ps; AD2[d] = pd; }
    if (lane < 16) {
        half8 hv;
#pragma unroll
        for (int i = 0; i < 8; ++i) hv[i] = (_Float16)y[i];
        *(half8*)(&Y[wave][tx * 8]) = hv;
    }
    __syncthreads();
    // epilogue GEMM: waves 0-7 each compute one 16-col tile of Y(16x128)@W2
    if (wave < 8) {
        const half8* BP = (const half8*)Wpk2;
        f32x4 c4 = {};
#pragma unroll
        for (int ks = 0; ks < 4; ++ks) {
            half8 a = *(const half8*)(&Y[lane & 15][ks * 32 + (lane >> 4) * 8]);
            half8 b = BP[(ks * 8 + wave) * 64 + lane];
            c4 = __builtin_amdgcn_mfma_f32_16x16x32_f16(a, b, c4, 0, 0, 0);
        }
        int colb = lane & 15;
        int rowq = (lane >> 4) * 4;
#pragma unroll
        for (int r = 0; r < 4; ++r)
            H16out[(size_t)dd[rowq + r] * NF + wave * 16 + colb] = __float2half_rn(c4[r]);
    }
}

// ---------------- layer-2 aggregate (wave-per-dst, degree-ranked, fp32 out) ----------------
__global__ __launch_bounds__(256) void k_aggregate2(
    const __half* __restrict__ H16, const float* __restrict__ AS, const float* __restrict__ AD,
    const int* __restrict__ offB, const int* __restrict__ offE,
    const unsigned short* __restrict__ srcs, const int* __restrict__ perm,
    const float* __restrict__ bias, float* __restrict__ OUT) {
    int wave = threadIdx.x >> 6, lane = threadIdx.x & 63;
    int d = perm[blockIdx.x * 4 + wave];

    __shared__ float ssv[4][SCAPW];
    __shared__ unsigned short ssrc[4][SCAPW];

    int beg = offB[d], deg = offE[d] - beg;
    float ad = AD[d];

    float ls = 0.f;
    for (int i = lane; i < deg; i += 64) {
        int s = srcs[beg + i];
        float sv = AS[s] + ad;
        sv = (sv > 0.f) ? sv : 0.2f * sv;
        float e = __expf(fminf(sv, 60.f));
        if (i < SCAPW) { ssv[wave][i] = e; ssrc[wave][i] = (unsigned short)s; }
        ls += e;
    }
#pragma unroll
    for (int o = 1; o <= 32; o <<= 1) ls += __shfl_xor(ls, o);
    float slv = AS[d] + ad;
    slv = (slv > 0.f) ? slv : 0.2f * slv;
    float es = __expf(fminf(slv, 60.f));
    ls += es;
    float inv = 1.f / (ls + 1e-16f);

    int tx = lane & 15, u = lane >> 4;
    float acc[8] = {0.f, 0.f, 0.f, 0.f, 0.f, 0.f, 0.f, 0.f};
    for (int j0 = 0; j0 < deg; j0 += 8) {
        int i0 = j0 + u, i1 = j0 + 4 + u;
        float e0 = 0.f, e1 = 0.f;
        int s0 = 0, s1 = 0;
        bool v0 = i0 < deg, v1 = i1 < deg;
        if (v0) {
            if (i0 < SCAPW) { e0 = ssv[wave][i0]; s0 = ssrc[wave][i0]; }
            else {
                s0 = srcs[beg + i0];
                float sv = AS[s0] + ad;
                sv = (sv > 0.f) ? sv : 0.2f * sv;
                e0 = __expf(fminf(sv, 60.f));
            }
        }
        if (v1) {
            if (i1 < SCAPW) { e1 = ssv[wave][i1]; s1 = ssrc[wave][i1]; }
            else {
                s1 = srcs[beg + i1];
                float sv = AS[s1] + ad;
                sv = (sv > 0.f) ? sv : 0.2f * sv;
                e1 = __expf(fminf(sv, 60.f));
            }
        }
        union { float4 f; __half2 h[4]; } va, vb;
        if (v0) va.f = *reinterpret_cast<const float4*>(H16 + (size_t)s0 * NF + tx * 8);
        if (v1) vb.f = *reinterpret_cast<const float4*>(H16 + (size_t)s1 * NF + tx * 8);
        if (v0) {
            float2 f0 = __half22float2(va.h[0]);
            float2 f1 = __half22float2(va.h[1]);
            float2 f2 = __half22float2(va.h[2]);
            float2 f3 = __half22float2(va.h[3]);
            acc[0] = fmaf(e0, f0.x, acc[0]); acc[1] = fmaf(e0, f0.y, acc[1]);
            acc[2] = fmaf(e0, f1.x, acc[2]); acc[3] = fmaf(e0, f1.y, acc[3]);
            acc[4] = fmaf(e0, f2.x, acc[4]); acc[5] = fmaf(e0, f2.y, acc[5]);
            acc[6] = fmaf(e0, f3.x, acc[6]); acc[7] = fmaf(e0, f3.y, acc[7]);
        }
        if (v1) {
            float2 f0 = __half22float2(vb.h[0]);
            float2 f1 = __half22float2(vb.h[1]);
            float2 f2 = __half22float2(vb.h[2]);
            float2 f3 = __half22float2(vb.h[3]);
            acc[0] = fmaf(e1, f0.x, acc[0]); acc[1] = fmaf(e1, f0.y, acc[1]);
            acc[2] = fmaf(e1, f1.x, acc[2]); acc[3] = fmaf(e1, f1.y, acc[3]);
            acc[4] = fmaf(e1, f2.x, acc[4]); acc[5] = fmaf(e1, f2.y, acc[5]);
            acc[6] = fmaf(e1, f3.x, acc[6]); acc[7] = fmaf(e1, f3.y, acc[7]);
        }
    }
#pragma unroll
    for (int o = 16; o <= 32; o <<= 1) {
#pragma unroll
        for (int i = 0; i < 8; ++i) acc[i] += __shfl_xor(acc[i], o);
    }
    {
        union { float4 f; __half2 h[4]; } vs;
        vs.f = *reinterpret_cast<const float4*>(H16 + (size_t)d * NF + tx * 8);
        float2 f0 = __half22float2(vs.h[0]);
        float2 f1 = __half22float2(vs.h[1]);
        float2 f2 = __half22float2(vs.h[2]);
        float2 f3 = __half22float2(vs.h[3]);
        acc[0] = fmaf(es, f0.x, acc[0]); acc[1] = fmaf(es, f0.y, acc[1]);
        acc[2] = fmaf(es, f1.x, acc[2]); acc[3] = fmaf(es, f1.y, acc[3]);
        acc[4] = fmaf(es, f2.x, acc[4]); acc[5] = fmaf(es, f2.y, acc[5]);
        acc[6] = fmaf(es, f3.x, acc[6]); acc[7] = fmaf(es, f3.y, acc[7]);
    }
    if (lane < 16) {
        float o8[8];
#pragma unroll
        for (int i = 0; i < 8; ++i) o8[i] = acc[i] * inv + bias[tx * 8 + i];
        float4 w0 = {o8[0], o8[1], o8[2], o8[3]};
        float4 w1 = {o8[4], o8[5], o8[6], o8[7]};
        ((float4*)OUT)[(size_t)d * 32 + tx * 2]     = w0;
        ((float4*)OUT)[(size_t)d * 32 + tx * 2 + 1] = w1;
    }
}

extern "C" void kernel_launch(void* const* d_in, const int* in_sizes, int n_in,
                              void* d_out, int out_size, void* d_ws, size_t ws_size,
                              hipStream_t stream) {
    const float* x   = (const float*)d_in[0];
    const int*   ei  = (const int*)d_in[1];
    const float* W1  = (const float*)d_in[2];
    const float* as1 = (const float*)d_in[3];
    const float* ad1 = (const float*)d_in[4];
    const float* b1  = (const float*)d_in[5];
    const float* W2  = (const float*)d_in[6];
    const float* as2 = (const float*)d_in[7];
    const float* ad2 = (const float*)d_in[8];
    const float* b2  = (const float*)d_in[9];
    float* out = (float*)d_out;

    char* p = (char*)d_ws;
    auto alloc = [&](size_t bytes) { char* r = p; p += (bytes + 255) & ~size_t(255); return (void*)r; };
    int* bcur  = (int*)alloc(sizeof(int) * NB);
    int* offB  = (int*)alloc(sizeof(int) * N);
    int* offE  = (int*)alloc(sizeof(int) * N);
    int* perm  = (int*)alloc(sizeof(int) * N);
    unsigned short* srcs = (unsigned short*)alloc(sizeof(unsigned short) * (size_t)NB * CAP);
    __half* H16a  = (__half*)alloc(sizeof(__half) * (size_t)N * NF);
    __half* H16b  = (__half*)alloc(sizeof(__half) * (size_t)N * NF);
    __half* Wpk1  = (__half*)alloc(sizeof(__half) * NF * NF);
    __half* Wpk2  = (__half*)alloc(sizeof(__half) * NF * NF);
    float* AS1 = (float*)alloc(sizeof(float) * N);
    float* AD1 = (float*)alloc(sizeof(float) * N);
    float* AS2 = (float*)alloc(sizeof(float) * N);
    float* AD2 = (float*)alloc(sizeof(float) * N);
    float* w2as = (float*)alloc(sizeof(float) * NF);
    float* w2ad = (float*)alloc(sizeof(float) * NF);
    int* packed = (int*)alloc(sizeof(int) * (size_t)NB * CAP);

    hipMemsetAsync(bcur, 0, sizeof(int) * NB, stream);
    k_scatter_packw<<<NBLK + PACKW_BLKS + 1, 1024, 0, stream>>>(
        ei, bcur, packed, W1, W2, Wpk1, Wpk2, as2, ad2, w2as, w2ad);
    k_csr_gemm1<<<2 * GEMM1_BLKS, 512, 0, stream>>>(packed, bcur, offB, offE, srcs, perm,
                                                    x, Wpk1, as1, ad1, H16a, AS1, AD1);
    k_agg1_gemm2<<<N / 16, 1024, 0, stream>>>(H16a, AS1, AD1, offB, offE, srcs, perm,
                                              b1, Wpk2, w2as, w2ad, H16b, AS2, AD2);
    k_aggregate2<<<N / 4, 256, 0, stream>>>(H16b, AS2, AD2, offB, offE, srcs, perm, b2, out);
}

// Round 18
// 191.322 us; speedup vs baseline: 2.2120x; 1.0000x over previous
//
#include <hip/hip_runtime.h>
#include <hip/hip_fp16.h>

constexpr int N  = 50000;
constexpr int E  = 1600000;                 // self-loops handled analytically
constexpr int NF = 128;
constexpr int BSH = 128;                    // dsts per bucket
constexpr int NB = (N + BSH - 1) / BSH;     // 391 buckets
constexpr int CAP = 8192;                   // slots per bucket (mean ~4094, sigma 64)
constexpr int EPB  = 8192;                  // edges per block (binscatter)
constexpr int NBLK = (E + EPB - 1) / EPB;   // 196
constexpr int PACKW_BLKS = (2 * NF * NF + 1023) / 1024;  // 32
constexpr int GEMM1_BLKS = (N + 127) / 128; // 391
constexpr int SCAPW = 128;                  // per-wave edge stash in aggregate

typedef _Float16 half8 __attribute__((ext_vector_type(8)));
typedef float    f32x4 __attribute__((ext_vector_type(4)));

// ---------------- fused binscatter + weight packing + w2 projections ----------------
__global__ __launch_bounds__(1024) void k_scatter_packw(
    const int* __restrict__ ei, int* __restrict__ bcur, int* __restrict__ packed,
    const float* __restrict__ W1, const float* __restrict__ W2,
    __half* __restrict__ P1, __half* __restrict__ P2,
    const float* __restrict__ as2, const float* __restrict__ ad2,
    float* __restrict__ w2as, float* __restrict__ w2ad) {
    int t = threadIdx.x;
    if (blockIdx.x == NBLK + PACKW_BLKS) {  // ---- w2 projection path ----
        if (t < NF) {
            float ps = 0.f, pd = 0.f;
            for (int j = 0; j < NF; ++j) {
                float w = W2[t * NF + j];
                ps = fmaf(w, as2[j], ps);
                pd = fmaf(w, ad2[j], pd);
            }
            w2as[t] = ps; w2ad[t] = pd;
        }
        return;
    }
    if (blockIdx.x >= NBLK) {               // ---- packw path ----
        int tid = (blockIdx.x - NBLK) * 1024 + t;
        if (tid >= 2 * NF * NF) return;
        int which = tid >> 14;
        int id = tid & (NF * NF - 1);
        int k = id >> 7, n = id & 127;
        const float* W = which ? W2 : W1;
        __half* P = which ? P2 : P1;
        int ks = k >> 5, r = k & 31, ct = n >> 4;
        int lane = ((r >> 3) << 4) | (n & 15);
        int j = r & 7;
        P[((ks * 8 + ct) * 64 + lane) * 8 + j] = __float2half_rn(W[k * NF + n]);
        return;
    }
    // ---- binscatter path (real edges only; self-loops analytic) ----
    __shared__ int h[NB], lcur[NB], garr[NB];
    for (int i = t; i < NB; i += 1024) h[i] = 0;
    __syncthreads();
    int base = blockIdx.x * EPB;
    int pk[EPB / 1024];
    int bk[EPB / 1024];
#pragma unroll
    for (int k = 0; k < EPB / 1024; ++k) {
        int i = base + k * 1024 + t;
        if (i < E) {
            int s = ei[i], d = ei[E + i];
            bk[k] = d >> 7;
            pk[k] = s | ((d & (BSH - 1)) << 16);
            atomicAdd(&h[bk[k]], 1);
        } else bk[k] = -1;
    }
    __syncthreads();
    for (int i = t; i < NB; i += 1024) {
        lcur[i] = 0;
        garr[i] = i * CAP + (h[i] ? atomicAdd(&bcur[i], h[i]) : 0);
    }
    __syncthreads();
#pragma unroll
    for (int k = 0; k < EPB / 1024; ++k) {
        if (bk[k] >= 0) {
            int p = garr[bk[k]] + atomicAdd(&lcur[bk[k]], 1);
            packed[p] = pk[k];
        }
    }
}

// ---------------- shared GEMM wave body (16 rows x 128 cols) ----------------
template <typename AT>
__device__ __forceinline__ void gemm_rows16(
    const AT* __restrict__ A, const half8* __restrict__ BP,
    const float* __restrict__ asv, const float* __restrict__ adv,
    __half* __restrict__ H16, float* __restrict__ AS, float* __restrict__ AD,
    int base, int lane) {
    int row_a = base + (lane & 15);
    if (row_a >= N) row_a = N - 1;
    const AT* Arow = A + (size_t)row_a * NF;

    f32x4 acc[8] = {};
#pragma unroll
    for (int ks = 0; ks < 4; ++ks) {
        int eo = (ks * 4 + (lane >> 4)) * 8;
        half8 a;
        if constexpr (sizeof(AT) == 4) {
            float4 u = *(const float4*)(Arow + eo);
            float4 v = *(const float4*)(Arow + eo + 4);
            a[0] = (_Float16)u.x; a[1] = (_Float16)u.y; a[2] = (_Float16)u.z; a[3] = (_Float16)u.w;
            a[4] = (_Float16)v.x; a[5] = (_Float16)v.y; a[6] = (_Float16)v.z; a[7] = (_Float16)v.w;
        } else {
            a = ((const half8*)Arow)[ks * 4 + (lane >> 4)];
        }
#pragma unroll
        for (int ct = 0; ct < 8; ++ct) {
            half8 b = BP[(ks * 8 + ct) * 64 + lane];
            acc[ct] = __builtin_amdgcn_mfma_f32_16x16x32_f16(a, b, acc[ct], 0, 0, 0);
        }
    }

    int colb = lane & 15;
    int rowq = base + (lane >> 4) * 4;
    float ps[4] = {0.f, 0.f, 0.f, 0.f};
    float pd[4] = {0.f, 0.f, 0.f, 0.f};
#pragma unroll
    for (int ct = 0; ct < 8; ++ct) {
        int col = ct * 16 + colb;
        float av = asv[col], dv = adv[col];
#pragma unroll
        for (int r = 0; r < 4; ++r) {
            float hv = acc[ct][r];
            if (rowq + r < N) H16[(size_t)(rowq + r) * NF + col] = __float2half_rn(hv);
            ps[r] = fmaf(hv, av, ps[r]);
            pd[r] = fmaf(hv, dv, pd[r]);
        }
    }
#pragma unroll
    for (int r = 0; r < 4; ++r) {
#pragma unroll
        for (int o = 1; o <= 8; o <<= 1) {
            ps[r] += __shfl_xor(ps[r], o);
            pd[r] += __shfl_xor(pd[r], o);
        }
    }
    if (colb == 0) {
#pragma unroll
        for (int r = 0; r < 4; ++r) {
            if (rowq + r < N) { AS[rowq + r] = ps[r]; AD[rowq + r] = pd[r]; }
        }
    }
}

// ---------------- fused k_csr + layer-1 GEMM (even/odd split) ----------------
// csr path also builds the bucket-local degree-rank permutation (NO atomics).
__global__ __launch_bounds__(512) void k_csr_gemm1(
    const int* __restrict__ packed, const int* __restrict__ bcur,
    int* __restrict__ offB, int* __restrict__ offE, unsigned short* __restrict__ srcs,
    int* __restrict__ perm,
    const float* __restrict__ X, const __half* __restrict__ Wpk,
    const float* __restrict__ asv, const float* __restrict__ adv,
    __half* __restrict__ H16, float* __restrict__ AS, float* __restrict__ AD) {
    int t = threadIdx.x;
    if ((blockIdx.x & 1) == 0) {            // ---- GEMM1 path ----
        int blk = blockIdx.x >> 1;
        int wave = t >> 6, lane = t & 63;
        int base = blk * 128 + wave * 16;
        gemm_rows16<float>(X, (const half8*)Wpk, asv, adv, H16, AS, AD, base, lane);
        return;
    }
    // ---- csr path ----
    int b = blockIdx.x >> 1;
    int s0 = b * CAP;
    int n = bcur[b];
    __shared__ int buf[CAP];
    __shared__ int h[BSH], bas[BSH], lcur[BSH];
    for (int i = t; i < n; i += 512) buf[i] = packed[s0 + i];
    if (t < BSH) { h[t] = 0; lcur[t] = 0; }
    __syncthreads();
    for (int i = t; i < n; i += 512)
        atomicAdd(&h[(buf[i] >> 16) & (BSH - 1)], 1);
    __syncthreads();
    // bucket-local degree-rank permutation (O(128) LDS scan per dst, no atomics)
    if (t < BSH) {
        int d = b * BSH + t;
        if (d < N) {
            int mydeg = h[t];
            int rank = 0;
            for (int j = 0; j < BSH; ++j) {
                if (b * BSH + j < N) {
                    int hj = h[j];
                    rank += (hj < mydeg) || (hj == mydeg && j < t);
                }
            }
            perm[b * BSH + rank] = d;
        }
    }
    if (t < 64) {                           // one wave scans 128 bins, 2 per lane
        int v0 = h[2 * t], v1 = h[2 * t + 1];
        int pair = v0 + v1, x = pair;
#pragma unroll
        for (int o = 1; o < 64; o <<= 1) {
            int y = __shfl_up(x, o);
            if (t >= o) x += y;
        }
        int e0 = s0 + x - pair;
        int e1 = e0 + v0;
        bas[2 * t] = e0; bas[2 * t + 1] = e1;
        int d = b * BSH + 2 * t;
        if (d < N)     { offB[d] = e0;     offE[d] = e1; }
        if (d + 1 < N) { offB[d + 1] = e1; offE[d + 1] = s0 + x; }
    }
    __syncthreads();
    for (int i = t; i < n; i += 512) {
        int p = buf[i];
        int dl = (p >> 16) & (BSH - 1);
        int pos = bas[dl] + atomicAdd(&lcur[dl], 1);
        srcs[pos] = (unsigned short)(p & 0xFFFF);
    }
}

// ---------------- aggregate-1 fused with layer-2 GEMM (degree-ranked dsts) ----------------
__global__ __launch_bounds__(1024) void k_agg1_gemm2(
    const __half* __restrict__ H16in, const float* __restrict__ AS, const float* __restrict__ AD,
    const int* __restrict__ offB, const int* __restrict__ offE,
    const unsigned short* __restrict__ srcs, const int* __restrict__ perm,
    const float* __restrict__ b1, const __half* __restrict__ Wpk2,
    const float* __restrict__ w2as, const float* __restrict__ w2ad,
    __half* __restrict__ H16out, float* __restrict__ AS2, float* __restrict__ AD2) {
    int wave = threadIdx.x >> 6, lane = threadIdx.x & 63;
    int d = perm[blockIdx.x * 16 + wave];   // N % 16 == 0

    __shared__ float ssv[16][SCAPW];
    __shared__ unsigned short ssrc[16][SCAPW];
    __shared__ __half Y[16][136];
    __shared__ int dd[16];
    if (lane == 0) dd[wave] = d;

    int beg = offB[d], deg = offE[d] - beg;
    float ad = AD[d];

    // pass 1: one exp per edge, stash, wave-reduce denominator
    float ls = 0.f;
    for (int i = lane; i < deg; i += 64) {
        int s = srcs[beg + i];
        float sv = AS[s] + ad;
        sv = (sv > 0.f) ? sv : 0.2f * sv;
        float e = __expf(fminf(sv, 60.f));
        if (i < SCAPW) { ssv[wave][i] = e; ssrc[wave][i] = (unsigned short)s; }
        ls += e;
    }
#pragma unroll
    for (int o = 1; o <= 32; o <<= 1) ls += __shfl_xor(ls, o);
    // analytic self-loop
    float slv = AS[d] + ad;
    slv = (slv > 0.f) ? slv : 0.2f * slv;
    float es = __expf(fminf(slv, 60.f));
    ls += es;
    float inv = 1.f / (ls + 1e-16f);

    // pass 2: gather-accumulate, 2x unrolled
    int tx = lane & 15, u = lane >> 4;
    float acc[8] = {0.f, 0.f, 0.f, 0.f, 0.f, 0.f, 0.f, 0.f};
    for (int j0 = 0; j0 < deg; j0 += 8) {
        int i0 = j0 + u, i1 = j0 + 4 + u;
        float e0 = 0.f, e1 = 0.f;
        int s0 = 0, s1 = 0;
        bool v0 = i0 < deg, v1 = i1 < deg;
        if (v0) {
            if (i0 < SCAPW) { e0 = ssv[wave][i0]; s0 = ssrc[wave][i0]; }
            else {
                s0 = srcs[beg + i0];
                float sv = AS[s0] + ad;
                sv = (sv > 0.f) ? sv : 0.2f * sv;
                e0 = __expf(fminf(sv, 60.f));
            }
        }
        if (v1) {
            if (i1 < SCAPW) { e1 = ssv[wave][i1]; s1 = ssrc[wave][i1]; }
            else {
                s1 = srcs[beg + i1];
                float sv = AS[s1] + ad;
                sv = (sv > 0.f) ? sv : 0.2f * sv;
                e1 = __expf(fminf(sv, 60.f));
            }
        }
        union { float4 f; __half2 h[4]; } va, vb;
        if (v0) va.f = *reinterpret_cast<const float4*>(H16in + (size_t)s0 * NF + tx * 8);
        if (v1) vb.f = *reinterpret_cast<const float4*>(H16in + (size_t)s1 * NF + tx * 8);
        if (v0) {
            float2 f0 = __half22float2(va.h[0]);
            float2 f1 = __half22float2(va.h[1]);
            float2 f2 = __half22float2(va.h[2]);
            float2 f3 = __half22float2(va.h[3]);
            acc[0] = fmaf(e0, f0.x, acc[0]); acc[1] = fmaf(e0, f0.y, acc[1]);
            acc[2] = fmaf(e0, f1.x, acc[2]); acc[3] = fmaf(e0, f1.y, acc[3]);
            acc[4] = fmaf(e0, f2.x, acc[4]); acc[5] = fmaf(e0, f2.y, acc[5]);
            acc[6] = fmaf(e0, f3.x, acc[6]); acc[7] = fmaf(e0, f3.y, acc[7]);
        }
        if (v1) {
            float2 f0 = __half22float2(vb.h[0]);
            float2 f1 = __half22float2(vb.h[1]);
            float2 f2 = __half22float2(vb.h[2]);
            float2 f3 = __half22float2(vb.h[3]);
            acc[0] = fmaf(e1, f0.x, acc[0]); acc[1] = fmaf(e1, f0.y, acc[1]);
            acc[2] = fmaf(e1, f1.x, acc[2]); acc[3] = fmaf(e1, f1.y, acc[3]);
            acc[4] = fmaf(e1, f2.x, acc[4]); acc[5] = fmaf(e1, f2.y, acc[5]);
            acc[6] = fmaf(e1, f3.x, acc[6]); acc[7] = fmaf(e1, f3.y, acc[7]);
        }
    }
#pragma unroll
    for (int o = 16; o <= 32; o <<= 1) {
#pragma unroll
        for (int i = 0; i < 8; ++i) acc[i] += __shfl_xor(acc[i], o);
    }
    // self contribution
    {
        union { float4 f; __half2 h[4]; } vs;
        vs.f = *reinterpret_cast<const float4*>(H16in + (size_t)d * NF + tx * 8);
        float2 f0 = __half22float2(vs.h[0]);
        float2 f1 = __half22float2(vs.h[1]);
        float2 f2 = __half22float2(vs.h[2]);
        float2 f3 = __half22float2(vs.h[3]);
        acc[0] = fmaf(es, f0.x, acc[0]); acc[1] = fmaf(es, f0.y, acc[1]);
        acc[2] = fmaf(es, f1.x, acc[2]); acc[3] = fmaf(es, f1.y, acc[3]);
        acc[4] = fmaf(es, f2.x, acc[4]); acc[5] = fmaf(es, f2.y, acc[5]);
        acc[6] = fmaf(es, f3.x, acc[6]); acc[7] = fmaf(es, f3.y, acc[7]);
    }
    // epilogue math: y = leaky(acc*inv + b1); alpha-2 via precomputed projections
    float y[8];
    float ps = 0.f, pd = 0.f;
#pragma unroll
    for (int i = 0; i < 8; ++i) {
        float v = acc[i] * inv + b1[tx * 8 + i];
        v = (v < 0.f) ? 0.01f * v : v;
        y[i] = v;
        ps = fmaf(v, w2as[tx * 8 + i], ps);
        pd = fmaf(v, w2ad[tx * 8 + i], pd);
    }
#pragma unroll
    for (int o = 1; o <= 8; o <<= 1) { ps += __shfl_xor(ps, o); pd += __shfl_xor(pd, o); }
    if (lane == 0) { AS2[d] = ps; AD2[d] = pd; }
    if (lane < 16) {
        half8 hv;
#pragma unroll
        for (int i = 0; i < 8; ++i) hv[i] = (_Float16)y[i];
        *(half8*)(&Y[wave][tx * 8]) = hv;
    }
    __syncthreads();
    // epilogue GEMM: waves 0-7 each compute one 16-col tile of Y(16x128)@W2
    if (wave < 8) {
        const half8* BP = (const half8*)Wpk2;
        f32x4 c4 = {};
#pragma unroll
        for (int ks = 0; ks < 4; ++ks) {
            half8 a = *(const half8*)(&Y[lane & 15][ks * 32 + (lane >> 4) * 8]);
            half8 b = BP[(ks * 8 + wave) * 64 + lane];
            c4 = __builtin_amdgcn_mfma_f32_16x16x32_f16(a, b, c4, 0, 0, 0);
        }
        int colb = lane & 15;
        int rowq = (lane >> 4) * 4;
#pragma unroll
        for (int r = 0; r < 4; ++r)
            H16out[(size_t)dd[rowq + r] * NF + wave * 16 + colb] = __float2half_rn(c4[r]);
    }
}

// ---------------- layer-2 aggregate (wave-per-dst, degree-ranked, fp32 out) ----------------
__global__ __launch_bounds__(256) void k_aggregate2(
    const __half* __restrict__ H16, const float* __restrict__ AS, const float* __restrict__ AD,
    const int* __restrict__ offB, const int* __restrict__ offE,
    const unsigned short* __restrict__ srcs, const int* __restrict__ perm,
    const float* __restrict__ bias, float* __restrict__ OUT) {
    int wave = threadIdx.x >> 6, lane = threadIdx.x & 63;
    int d = perm[blockIdx.x * 4 + wave];

    __shared__ float ssv[4][SCAPW];
    __shared__ unsigned short ssrc[4][SCAPW];

    int beg = offB[d], deg = offE[d] - beg;
    float ad = AD[d];

    float ls = 0.f;
    for (int i = lane; i < deg; i += 64) {
        int s = srcs[beg + i];
        float sv = AS[s] + ad;
        sv = (sv > 0.f) ? sv : 0.2f * sv;
        float e = __expf(fminf(sv, 60.f));
        if (i < SCAPW) { ssv[wave][i] = e; ssrc[wave][i] = (unsigned short)s; }
        ls += e;
    }
#pragma unroll
    for (int o = 1; o <= 32; o <<= 1) ls += __shfl_xor(ls, o);
    float slv = AS[d] + ad;
    slv = (slv > 0.f) ? slv : 0.2f * slv;
    float es = __expf(fminf(slv, 60.f));
    ls += es;
    float inv = 1.f / (ls + 1e-16f);

    int tx = lane & 15, u = lane >> 4;
    float acc[8] = {0.f, 0.f, 0.f, 0.f, 0.f, 0.f, 0.f, 0.f};
    for (int j0 = 0; j0 < deg; j0 += 8) {
        int i0 = j0 + u, i1 = j0 + 4 + u;
        float e0 = 0.f, e1 = 0.f;
        int s0 = 0, s1 = 0;
        bool v0 = i0 < deg, v1 = i1 < deg;
        if (v0) {
            if (i0 < SCAPW) { e0 = ssv[wave][i0]; s0 = ssrc[wave][i0]; }
            else {
                s0 = srcs[beg + i0];
                float sv = AS[s0] + ad;
                sv = (sv > 0.f) ? sv : 0.2f * sv;
                e0 = __expf(fminf(sv, 60.f));
            }
        }
        if (v1) {
            if (i1 < SCAPW) { e1 = ssv[wave][i1]; s1 = ssrc[wave][i1]; }
            else {
                s1 = srcs[beg + i1];
                float sv = AS[s1] + ad;
                sv = (sv > 0.f) ? sv : 0.2f * sv;
                e1 = __expf(fminf(sv, 60.f));
            }
        }
        union { float4 f; __half2 h[4]; } va, vb;
        if (v0) va.f = *reinterpret_cast<const float4*>(H16 + (size_t)s0 * NF + tx * 8);
        if (v1) vb.f = *reinterpret_cast<const float4*>(H16 + (size_t)s1 * NF + tx * 8);
        if (v0) {
            float2 f0 = __half22float2(va.h[0]);
            float2 f1 = __half22float2(va.h[1]);
            float2 f2 = __half22float2(va.h[2]);
            float2 f3 = __half22float2(va.h[3]);
            acc[0] = fmaf(e0, f0.x, acc[0]); acc[1] = fmaf(e0, f0.y, acc[1]);
            acc[2] = fmaf(e0, f1.x, acc[2]); acc[3] = fmaf(e0, f1.y, acc[3]);
            acc[4] = fmaf(e0, f2.x, acc[4]); acc[5] = fmaf(e0, f2.y, acc[5]);
            acc[6] = fmaf(e0, f3.x, acc[6]); acc[7] = fmaf(e0, f3.y, acc[7]);
        }
        if (v1) {
            float2 f0 = __half22float2(vb.h[0]);
            float2 f1 = __half22float2(vb.h[1]);
            float2 f2 = __half22float2(vb.h[2]);
            float2 f3 = __half22float2(vb.h[3]);
            acc[0] = fmaf(e1, f0.x, acc[0]); acc[1] = fmaf(e1, f0.y, acc[1]);
            acc[2] = fmaf(e1, f1.x, acc[2]); acc[3] = fmaf(e1, f1.y, acc[3]);
            acc[4] = fmaf(e1, f2.x, acc[4]); acc[5] = fmaf(e1, f2.y, acc[5]);
            acc[6] = fmaf(e1, f3.x, acc[6]); acc[7] = fmaf(e1, f3.y, acc[7]);
        }
    }
#pragma unroll
    for (int o = 16; o <= 32; o <<= 1) {
#pragma unroll
        for (int i = 0; i < 8; ++i) acc[i] += __shfl_xor(acc[i], o);
    }
    {
        union { float4 f; __half2 h[4]; } vs;
        vs.f = *reinterpret_cast<const float4*>(H16 + (size_t)d * NF + tx * 8);
        float2 f0 = __half22float2(vs.h[0]);
        float2 f1 = __half22float2(vs.h[1]);
        float2 f2 = __half22float2(vs.h[2]);
        float2 f3 = __half22float2(vs.h[3]);
        acc[0] = fmaf(es, f0.x, acc[0]); acc[1] = fmaf(es, f0.y, acc[1]);
        acc[2] = fmaf(es, f1.x, acc[2]); acc[3] = fmaf(es, f1.y, acc[3]);
        acc[4] = fmaf(es, f2.x, acc[4]); acc[5] = fmaf(es, f2.y, acc[5]);
        acc[6] = fmaf(es, f3.x, acc[6]); acc[7] = fmaf(es, f3.y, acc[7]);
    }
    if (lane < 16) {
        float o8[8];
#pragma unroll
        for (int i = 0; i < 8; ++i) o8[i] = acc[i] * inv + bias[tx * 8 + i];
        float4 w0 = {o8[0], o8[1], o8[2], o8[3]};
        float4 w1 = {o8[4], o8[5], o8[6], o8[7]};
        ((float4*)OUT)[(size_t)d * 32 + tx * 2]     = w0;
        ((float4*)OUT)[(size_t)d * 32 + tx * 2 + 1] = w1;
    }
}

extern "C" void kernel_launch(void* const* d_in, const int* in_sizes, int n_in,
                              void* d_out, int out_size, void* d_ws, size_t ws_size,
                              hipStream_t stream) {
    const float* x   = (const float*)d_in[0];
    const int*   ei  = (const int*)d_in[1];
    const float* W1  = (const float*)d_in[2];
    const float* as1 = (const float*)d_in[3];
    const float* ad1 = (const float*)d_in[4];
    const float* b1  = (const float*)d_in[5];
    const float* W2  = (const float*)d_in[6];
    const float* as2 = (const float*)d_in[7];
    const float* ad2 = (const float*)d_in[8];
    const float* b2  = (const float*)d_in[9];
    float* out = (float*)d_out;

    char* p = (char*)d_ws;
    auto alloc = [&](size_t bytes) { char* r = p; p += (bytes + 255) & ~size_t(255); return (void*)r; };
    int* bcur  = (int*)alloc(sizeof(int) * NB);
    int* offB  = (int*)alloc(sizeof(int) * N);
    int* offE  = (int*)alloc(sizeof(int) * N);
    int* perm  = (int*)alloc(sizeof(int) * N);
    unsigned short* srcs = (unsigned short*)alloc(sizeof(unsigned short) * (size_t)NB * CAP);
    __half* H16a  = (__half*)alloc(sizeof(__half) * (size_t)N * NF);
    __half* H16b  = (__half*)alloc(sizeof(__half) * (size_t)N * NF);
    __half* Wpk1  = (__half*)alloc(sizeof(__half) * NF * NF);
    __half* Wpk2  = (__half*)alloc(sizeof(__half) * NF * NF);
    float* AS1 = (float*)alloc(sizeof(float) * N);
    float* AD1 = (float*)alloc(sizeof(float) * N);
    float* AS2 = (float*)alloc(sizeof(float) * N);
    float* AD2 = (float*)alloc(sizeof(float) * N);
    float* w2as = (float*)alloc(sizeof(float) * NF);
    float* w2ad = (float*)alloc(sizeof(float) * NF);
    int* packed = (int*)alloc(sizeof(int) * (size_t)NB * CAP);

    hipMemsetAsync(bcur, 0, sizeof(int) * NB, stream);
    k_scatter_packw<<<NBLK + PACKW_BLKS + 1, 1024, 0, stream>>>(
        ei, bcur, packed, W1, W2, Wpk1, Wpk2, as2, ad2, w2as, w2ad);
    k_csr_gemm1<<<2 * GEMM1_BLKS, 512, 0, stream>>>(packed, bcur, offB, offE, srcs, perm,
                                                    x, Wpk1, as1, ad1, H16a, AS1, AD1);
    k_agg1_gemm2<<<N / 16, 1024, 0, stream>>>(H16a, AS1, AD1, offB, offE, srcs, perm,
                                              b1, Wpk2, w2as, w2ad, H16b, AS2, AD2);
    k_aggregate2<<<N / 4, 256, 0, stream>>>(H16b, AS2, AD2, offB, offE, srcs, perm, b2, out);
}

// Round 19
// 190.969 us; speedup vs baseline: 2.2161x; 1.0019x over previous
//
#include <hip/hip_runtime.h>
#include <hip/hip_fp16.h>

constexpr int N  = 50000;
constexpr int E  = 1600000;                 // self-loops handled analytically
constexpr int NF = 128;
constexpr int BSH = 128;                    // dsts per bucket
constexpr int NB = (N + BSH - 1) / BSH;     // 391 buckets
constexpr int CAP = 8192;                   // slots per bucket (mean ~4094, sigma 64)
constexpr int EPB  = 8192;                  // edges per block (binscatter)
constexpr int NBLK = (E + EPB - 1) / EPB;   // 196
constexpr int PACKW_BLKS = (2 * NF * NF + 1023) / 1024;  // 32
constexpr int GEMM1_BLKS = (N + 127) / 128; // 391
constexpr int SCAPW = 128;                  // per-wave edge stash in aggregate

typedef _Float16 half8 __attribute__((ext_vector_type(8)));
typedef float    f32x4 __attribute__((ext_vector_type(4)));

// ---------------- fused binscatter + weight packing + w2 projections ----------------
__global__ __launch_bounds__(1024) void k_scatter_packw(
    const int* __restrict__ ei, int* __restrict__ bcur, int* __restrict__ packed,
    const float* __restrict__ W1, const float* __restrict__ W2,
    __half* __restrict__ P1, __half* __restrict__ P2,
    const float* __restrict__ as2, const float* __restrict__ ad2,
    float* __restrict__ w2as, float* __restrict__ w2ad) {
    int t = threadIdx.x;
    if (blockIdx.x == NBLK + PACKW_BLKS) {  // ---- w2 projection path ----
        if (t < NF) {
            float ps = 0.f, pd = 0.f;
            for (int j = 0; j < NF; ++j) {
                float w = W2[t * NF + j];
                ps = fmaf(w, as2[j], ps);
                pd = fmaf(w, ad2[j], pd);
            }
            w2as[t] = ps; w2ad[t] = pd;
        }
        return;
    }
    if (blockIdx.x >= NBLK) {               // ---- packw path ----
        int tid = (blockIdx.x - NBLK) * 1024 + t;
        if (tid >= 2 * NF * NF) return;
        int which = tid >> 14;
        int id = tid & (NF * NF - 1);
        int k = id >> 7, n = id & 127;
        const float* W = which ? W2 : W1;
        __half* P = which ? P2 : P1;
        int ks = k >> 5, r = k & 31, ct = n >> 4;
        int lane = ((r >> 3) << 4) | (n & 15);
        int j = r & 7;
        P[((ks * 8 + ct) * 64 + lane) * 8 + j] = __float2half_rn(W[k * NF + n]);
        return;
    }
    // ---- binscatter path (real edges only; self-loops analytic) ----
    __shared__ int h[NB], lcur[NB], garr[NB];
    for (int i = t; i < NB; i += 1024) h[i] = 0;
    __syncthreads();
    int base = blockIdx.x * EPB;
    int pk[EPB / 1024];
    int bk[EPB / 1024];
#pragma unroll
    for (int k = 0; k < EPB / 1024; ++k) {
        int i = base + k * 1024 + t;
        if (i < E) {
            int s = ei[i], d = ei[E + i];
            bk[k] = d >> 7;
            pk[k] = s | ((d & (BSH - 1)) << 16);
            atomicAdd(&h[bk[k]], 1);
        } else bk[k] = -1;
    }
    __syncthreads();
    for (int i = t; i < NB; i += 1024) {
        lcur[i] = 0;
        garr[i] = i * CAP + (h[i] ? atomicAdd(&bcur[i], h[i]) : 0);
    }
    __syncthreads();
#pragma unroll
    for (int k = 0; k < EPB / 1024; ++k) {
        if (bk[k] >= 0) {
            int p = garr[bk[k]] + atomicAdd(&lcur[bk[k]], 1);
            packed[p] = pk[k];
        }
    }
}

// ---------------- shared GEMM wave body (16 rows x 128 cols) ----------------
template <typename AT>
__device__ __forceinline__ void gemm_rows16(
    const AT* __restrict__ A, const half8* __restrict__ BP,
    const float* __restrict__ asv, const float* __restrict__ adv,
    __half* __restrict__ H16, float* __restrict__ AS, float* __restrict__ AD,
    int base, int lane) {
    int row_a = base + (lane & 15);
    if (row_a >= N) row_a = N - 1;
    const AT* Arow = A + (size_t)row_a * NF;

    f32x4 acc[8] = {};
#pragma unroll
    for (int ks = 0; ks < 4; ++ks) {
        int eo = (ks * 4 + (lane >> 4)) * 8;
        half8 a;
        if constexpr (sizeof(AT) == 4) {
            float4 u = *(const float4*)(Arow + eo);
            float4 v = *(const float4*)(Arow + eo + 4);
            a[0] = (_Float16)u.x; a[1] = (_Float16)u.y; a[2] = (_Float16)u.z; a[3] = (_Float16)u.w;
            a[4] = (_Float16)v.x; a[5] = (_Float16)v.y; a[6] = (_Float16)v.z; a[7] = (_Float16)v.w;
        } else {
            a = ((const half8*)Arow)[ks * 4 + (lane >> 4)];
        }
#pragma unroll
        for (int ct = 0; ct < 8; ++ct) {
            half8 b = BP[(ks * 8 + ct) * 64 + lane];
            acc[ct] = __builtin_amdgcn_mfma_f32_16x16x32_f16(a, b, acc[ct], 0, 0, 0);
        }
    }

    int colb = lane & 15;
    int rowq = base + (lane >> 4) * 4;
    float ps[4] = {0.f, 0.f, 0.f, 0.f};
    float pd[4] = {0.f, 0.f, 0.f, 0.f};
#pragma unroll
    for (int ct = 0; ct < 8; ++ct) {
        int col = ct * 16 + colb;
        float av = asv[col], dv = adv[col];
#pragma unroll
        for (int r = 0; r < 4; ++r) {
            float hv = acc[ct][r];
            if (rowq + r < N) H16[(size_t)(rowq + r) * NF + col] = __float2half_rn(hv);
            ps[r] = fmaf(hv, av, ps[r]);
            pd[r] = fmaf(hv, dv, pd[r]);
        }
    }
#pragma unroll
    for (int r = 0; r < 4; ++r) {
#pragma unroll
        for (int o = 1; o <= 8; o <<= 1) {
            ps[r] += __shfl_xor(ps[r], o);
            pd[r] += __shfl_xor(pd[r], o);
        }
    }
    if (colb == 0) {
#pragma unroll
        for (int r = 0; r < 4; ++r) {
            if (rowq + r < N) { AS[rowq + r] = ps[r]; AD[rowq + r] = pd[r]; }
        }
    }
}

// ---------------- fused k_csr + layer-1 GEMM (even/odd split) ----------------
// csr path also builds the bucket-local degree-rank permutation (NO atomics).
__global__ __launch_bounds__(512) void k_csr_gemm1(
    const int* __restrict__ packed, const int* __restrict__ bcur,
    int* __restrict__ offB, int* __restrict__ offE, unsigned short* __restrict__ srcs,
    int* __restrict__ perm,
    const float* __restrict__ X, const __half* __restrict__ Wpk,
    const float* __restrict__ asv, const float* __restrict__ adv,
    __half* __restrict__ H16, float* __restrict__ AS, float* __restrict__ AD) {
    int t = threadIdx.x;
    if ((blockIdx.x & 1) == 0) {            // ---- GEMM1 path ----
        int blk = blockIdx.x >> 1;
        int wave = t >> 6, lane = t & 63;
        int base = blk * 128 + wave * 16;
        gemm_rows16<float>(X, (const half8*)Wpk, asv, adv, H16, AS, AD, base, lane);
        return;
    }
    // ---- csr path ----
    int b = blockIdx.x >> 1;
    int s0 = b * CAP;
    int n = bcur[b];
    __shared__ int buf[CAP];
    __shared__ int h[BSH], bas[BSH], lcur[BSH];
    for (int i = t; i < n; i += 512) buf[i] = packed[s0 + i];
    if (t < BSH) { h[t] = 0; lcur[t] = 0; }
    __syncthreads();
    for (int i = t; i < n; i += 512)
        atomicAdd(&h[(buf[i] >> 16) & (BSH - 1)], 1);
    __syncthreads();
    // bucket-local degree-rank permutation (O(128) LDS scan per dst, no atomics)
    if (t < BSH) {
        int d = b * BSH + t;
        if (d < N) {
            int mydeg = h[t];
            int rank = 0;
            for (int j = 0; j < BSH; ++j) {
                if (b * BSH + j < N) {
                    int hj = h[j];
                    rank += (hj < mydeg) || (hj == mydeg && j < t);
                }
            }
            perm[b * BSH + rank] = d;
        }
    }
    if (t < 64) {                           // one wave scans 128 bins, 2 per lane
        int v0 = h[2 * t], v1 = h[2 * t + 1];
        int pair = v0 + v1, x = pair;
#pragma unroll
        for (int o = 1; o < 64; o <<= 1) {
            int y = __shfl_up(x, o);
            if (t >= o) x += y;
        }
        int e0 = s0 + x - pair;
        int e1 = e0 + v0;
        bas[2 * t] = e0; bas[2 * t + 1] = e1;
        int d = b * BSH + 2 * t;
        if (d < N)     { offB[d] = e0;     offE[d] = e1; }
        if (d + 1 < N) { offB[d + 1] = e1; offE[d + 1] = s0 + x; }
    }
    __syncthreads();
    for (int i = t; i < n; i += 512) {
        int p = buf[i];
        int dl = (p >> 16) & (BSH - 1);
        int pos = bas[dl] + atomicAdd(&lcur[dl], 1);
        srcs[pos] = (unsigned short)(p & 0xFFFF);
    }
}

// ---------------- aggregate-1 fused with layer-2 GEMM (degree-ranked dsts) ----------------
__global__ __launch_bounds__(1024) void k_agg1_gemm2(
    const __half* __restrict__ H16in, const float* __restrict__ AS, const float* __restrict__ AD,
    const int* __restrict__ offB, const int* __restrict__ offE,
    const unsigned short* __restrict__ srcs, const int* __restrict__ perm,
    const float* __restrict__ b1, const __half* __restrict__ Wpk2,
    const float* __restrict__ w2as, const float* __restrict__ w2ad,
    __half* __restrict__ H16out, float* __restrict__ AS2, float* __restrict__ AD2) {
    int wave = threadIdx.x >> 6, lane = threadIdx.x & 63;
    int d = perm[blockIdx.x * 16 + wave];   // N % 16 == 0

    __shared__ float ssv[16][SCAPW];
    __shared__ unsigned short ssrc[16][SCAPW];
    __shared__ __half Y[16][136];
    __shared__ int dd[16];
    if (lane == 0) dd[wave] = d;

    int beg = offB[d], deg = offE[d] - beg;
    float ad = AD[d];

    // pass 1: one exp per edge, stash, wave-reduce denominator
    float ls = 0.f;
    for (int i = lane; i < deg; i += 64) {
        int s = srcs[beg + i];
        float sv = AS[s] + ad;
        sv = (sv > 0.f) ? sv : 0.2f * sv;
        float e = __expf(fminf(sv, 60.f));
        if (i < SCAPW) { ssv[wave][i] = e; ssrc[wave][i] = (unsigned short)s; }
        ls += e;
    }
#pragma unroll
    for (int o = 1; o <= 32; o <<= 1) ls += __shfl_xor(ls, o);
    // analytic self-loop
    float slv = AS[d] + ad;
    slv = (slv > 0.f) ? slv : 0.2f * slv;
    float es = __expf(fminf(slv, 60.f));
    ls += es;
    float inv = 1.f / (ls + 1e-16f);

    // pass 2: gather-accumulate, 2x unrolled
    int tx = lane & 15, u = lane >> 4;
    float acc[8] = {0.f, 0.f, 0.f, 0.f, 0.f, 0.f, 0.f, 0.f};
    for (int j0 = 0; j0 < deg; j0 += 8) {
        int i0 = j0 + u, i1 = j0 + 4 + u;
        float e0 = 0.f, e1 = 0.f;
        int s0 = 0, s1 = 0;
        bool v0 = i0 < deg, v1 = i1 < deg;
        if (v0) {
            if (i0 < SCAPW) { e0 = ssv[wave][i0]; s0 = ssrc[wave][i0]; }
            else {
                s0 = srcs[beg + i0];
                float sv = AS[s0] + ad;
                sv = (sv > 0.f) ? sv : 0.2f * sv;
                e0 = __expf(fminf(sv, 60.f));
            }
        }
        if (v1) {
            if (i1 < SCAPW) { e1 = ssv[wave][i1]; s1 = ssrc[wave][i1]; }
            else {
                s1 = srcs[beg + i1];
                float sv = AS[s1] + ad;
                sv = (sv > 0.f) ? sv : 0.2f * sv;
                e1 = __expf(fminf(sv, 60.f));
            }
        }
        union { float4 f; __half2 h[4]; } va, vb;
        if (v0) va.f = *reinterpret_cast<const float4*>(H16in + (size_t)s0 * NF + tx * 8);
        if (v1) vb.f = *reinterpret_cast<const float4*>(H16in + (size_t)s1 * NF + tx * 8);
        if (v0) {
            float2 f0 = __half22float2(va.h[0]);
            float2 f1 = __half22float2(va.h[1]);
            float2 f2 = __half22float2(va.h[2]);
            float2 f3 = __half22float2(va.h[3]);
            acc[0] = fmaf(e0, f0.x, acc[0]); acc[1] = fmaf(e0, f0.y, acc[1]);
            acc[2] = fmaf(e0, f1.x, acc[2]); acc[3] = fmaf(e0, f1.y, acc[3]);
            acc[4] = fmaf(e0, f2.x, acc[4]); acc[5] = fmaf(e0, f2.y, acc[5]);
            acc[6] = fmaf(e0, f3.x, acc[6]); acc[7] = fmaf(e0, f3.y, acc[7]);
        }
        if (v1) {
            float2 f0 = __half22float2(vb.h[0]);
            float2 f1 = __half22float2(vb.h[1]);
            float2 f2 = __half22float2(vb.h[2]);
            float2 f3 = __half22float2(vb.h[3]);
            acc[0] = fmaf(e1, f0.x, acc[0]); acc[1] = fmaf(e1, f0.y, acc[1]);
            acc[2] = fmaf(e1, f1.x, acc[2]); acc[3] = fmaf(e1, f1.y, acc[3]);
            acc[4] = fmaf(e1, f2.x, acc[4]); acc[5] = fmaf(e1, f2.y, acc[5]);
            acc[6] = fmaf(e1, f3.x, acc[6]); acc[7] = fmaf(e1, f3.y, acc[7]);
        }
    }
#pragma unroll
    for (int o = 16; o <= 32; o <<= 1) {
#pragma unroll
        for (int i = 0; i < 8; ++i) acc[i] += __shfl_xor(acc[i], o);
    }
    // self contribution
    {
        union { float4 f; __half2 h[4]; } vs;
        vs.f = *reinterpret_cast<const float4*>(H16in + (size_t)d * NF + tx * 8);
        float2 f0 = __half22float2(vs.h[0]);
        float2 f1 = __half22float2(vs.h[1]);
        float2 f2 = __half22float2(vs.h[2]);
        float2 f3 = __half22float2(vs.h[3]);
        acc[0] = fmaf(es, f0.x, acc[0]); acc[1] = fmaf(es, f0.y, acc[1]);
        acc[2] = fmaf(es, f1.x, acc[2]); acc[3] = fmaf(es, f1.y, acc[3]);
        acc[4] = fmaf(es, f2.x, acc[4]); acc[5] = fmaf(es, f2.y, acc[5]);
        acc[6] = fmaf(es, f3.x, acc[6]); acc[7] = fmaf(es, f3.y, acc[7]);
    }
    // epilogue math: y = leaky(acc*inv + b1); alpha-2 via precomputed projections
    float y[8];
    float ps = 0.f, pd = 0.f;
#pragma unroll
    for (int i = 0; i < 8; ++i) {
        float v = acc[i] * inv + b1[tx * 8 + i];
        v = (v < 0.f) ? 0.01f * v : v;
        y[i] = v;
        ps = fmaf(v, w2as[tx * 8 + i], ps);
        pd = fmaf(v, w2ad[tx * 8 + i], pd);
    }
#pragma unroll
    for (int o = 1; o <= 8; o <<= 1) { ps += __shfl_xor(ps, o); pd += __shfl_xor(pd, o); }
    if (lane == 0) { AS2[d] = ps; AD2[d] = pd; }
    if (lane < 16) {
        half8 hv;
#pragma unroll
        for (int i = 0; i < 8; ++i) hv[i] = (_Float16)y[i];
        *(half8*)(&Y[wave][tx * 8]) = hv;
    }
    __syncthreads();
    // epilogue GEMM: waves 0-7 each compute one 16-col tile of Y(16x128)@W2
    if (wave < 8) {
        const half8* BP = (const half8*)Wpk2;
        f32x4 c4 = {};
#pragma unroll
        for (int ks = 0; ks < 4; ++ks) {
            half8 a = *(const half8*)(&Y[lane & 15][ks * 32 + (lane >> 4) * 8]);
            half8 b = BP[(ks * 8 + wave) * 64 + lane];
            c4 = __builtin_amdgcn_mfma_f32_16x16x32_f16(a, b, c4, 0, 0, 0);
        }
        int colb = lane & 15;
        int rowq = (lane >> 4) * 4;
#pragma unroll
        for (int r = 0; r < 4; ++r)
            H16out[(size_t)dd[rowq + r] * NF + wave * 16 + colb] = __float2half_rn(c4[r]);
    }
}

// ---------------- layer-2 aggregate (wave-per-dst, degree-ranked, fp32 out) ----------------
__global__ __launch_bounds__(256) void k_aggregate2(
    const __half* __restrict__ H16, const float* __restrict__ AS, const float* __restrict__ AD,
    const int* __restrict__ offB, const int* __restrict__ offE,
    const unsigned short* __restrict__ srcs, const int* __restrict__ perm,
    const float* __restrict__ bias, float* __restrict__ OUT) {
    int wave = threadIdx.x >> 6, lane = threadIdx.x & 63;
    int d = perm[blockIdx.x * 4 + wave];

    __shared__ float ssv[4][SCAPW];
    __shared__ unsigned short ssrc[4][SCAPW];

    int beg = offB[d], deg = offE[d] - beg;
    float ad = AD[d];

    float ls = 0.f;
    for (int i = lane; i < deg; i += 64) {
        int s = srcs[beg + i];
        float sv = AS[s] + ad;
        sv = (sv > 0.f) ? sv : 0.2f * sv;
        float e = __expf(fminf(sv, 60.f));
        if (i < SCAPW) { ssv[wave][i] = e; ssrc[wave][i] = (unsigned short)s; }
        ls += e;
    }
#pragma unroll
    for (int o = 1; o <= 32; o <<= 1) ls += __shfl_xor(ls, o);
    float slv = AS[d] + ad;
    slv = (slv > 0.f) ? slv : 0.2f * slv;
    float es = __expf(fminf(slv, 60.f));
    ls += es;
    float inv = 1.f / (ls + 1e-16f);

    int tx = lane & 15, u = lane >> 4;
    float acc[8] = {0.f, 0.f, 0.f, 0.f, 0.f, 0.f, 0.f, 0.f};
    for (int j0 = 0; j0 < deg; j0 += 8) {
        int i0 = j0 + u, i1 = j0 + 4 + u;
        float e0 = 0.f, e1 = 0.f;
        int s0 = 0, s1 = 0;
        bool v0 = i0 < deg, v1 = i1 < deg;
        if (v0) {
            if (i0 < SCAPW) { e0 = ssv[wave][i0]; s0 = ssrc[wave][i0]; }
            else {
                s0 = srcs[beg + i0];
                float sv = AS[s0] + ad;
                sv = (sv > 0.f) ? sv : 0.2f * sv;
                e0 = __expf(fminf(sv, 60.f));
            }
        }
        if (v1) {
            if (i1 < SCAPW) { e1 = ssv[wave][i1]; s1 = ssrc[wave][i1]; }
            else {
                s1 = srcs[beg + i1];
                float sv = AS[s1] + ad;
                sv = (sv > 0.f) ? sv : 0.2f * sv;
                e1 = __expf(fminf(sv, 60.f));
            }
        }
        union { float4 f; __half2 h[4]; } va, vb;
        if (v0) va.f = *reinterpret_cast<const float4*>(H16 + (size_t)s0 * NF + tx * 8);
        if (v1) vb.f = *reinterpret_cast<const float4*>(H16 + (size_t)s1 * NF + tx * 8);
        if (v0) {
            float2 f0 = __half22float2(va.h[0]);
            float2 f1 = __half22float2(va.h[1]);
            float2 f2 = __half22float2(va.h[2]);
            float2 f3 = __half22float2(va.h[3]);
            acc[0] = fmaf(e0, f0.x, acc[0]); acc[1] = fmaf(e0, f0.y, acc[1]);
            acc[2] = fmaf(e0, f1.x, acc[2]); acc[3] = fmaf(e0, f1.y, acc[3]);
            acc[4] = fmaf(e0, f2.x, acc[4]); acc[5] = fmaf(e0, f2.y, acc[5]);
            acc[6] = fmaf(e0, f3.x, acc[6]); acc[7] = fmaf(e0, f3.y, acc[7]);
        }
        if (v1) {
            float2 f0 = __half22float2(vb.h[0]);
            float2 f1 = __half22float2(vb.h[1]);
            float2 f2 = __half22float2(vb.h[2]);
            float2 f3 = __half22float2(vb.h[3]);
            acc[0] = fmaf(e1, f0.x, acc[0]); acc[1] = fmaf(e1, f0.y, acc[1]);
            acc[2] = fmaf(e1, f1.x, acc[2]); acc[3] = fmaf(e1, f1.y, acc[3]);
            acc[4] = fmaf(e1, f2.x, acc[4]); acc[5] = fmaf(e1, f2.y, acc[5]);
            acc[6] = fmaf(e1, f3.x, acc[6]); acc[7] = fmaf(e1, f3.y, acc[7]);
        }
    }
#pragma unroll
    for (int o = 16; o <= 32; o <<= 1) {
#pragma unroll
        for (int i = 0; i < 8; ++i) acc[i] += __shfl_xor(acc[i], o);
    }
    {
        union { float4 f; __half2 h[4]; } vs;
        vs.f = *reinterpret_cast<const float4*>(H16 + (size_t)d * NF + tx * 8);
        float2 f0 = __half22float2(vs.h[0]);
        float2 f1 = __half22float2(vs.h[1]);
        float2 f2 = __half22float2(vs.h[2]);
        float2 f3 = __half22float2(vs.h[3]);
        acc[0] = fmaf(es, f0.x, acc[0]); acc[1] = fmaf(es, f0.y, acc[1]);
        acc[2] = fmaf(es, f1.x, acc[2]); acc[3] = fmaf(es, f1.y, acc[3]);
        acc[4] = fmaf(es, f2.x, acc[4]); acc[5] = fmaf(es, f2.y, acc[5]);
        acc[6] = fmaf(es, f3.x, acc[6]); acc[7] = fmaf(es, f3.y, acc[7]);
    }
    if (lane < 16) {
        float o8[8];
#pragma unroll
        for (int i = 0; i < 8; ++i) o8[i] = acc[i] * inv + bias[tx * 8 + i];
        float4 w0 = {o8[0], o8[1], o8[2], o8[3]};
        float4 w1 = {o8[4], o8[5], o8[6], o8[7]};
        ((float4*)OUT)[(size_t)d * 32 + tx * 2]     = w0;
        ((float4*)OUT)[(size_t)d * 32 + tx * 2 + 1] = w1;
    }
}

extern "C" void kernel_launch(void* const* d_in, const int* in_sizes, int n_in,
                              void* d_out, int out_size, void* d_ws, size_t ws_size,
                              hipStream_t stream) {
    const float* x   = (const float*)d_in[0];
    const int*   ei  = (const int*)d_in[1];
    const float* W1  = (const float*)d_in[2];
    const float* as1 = (const float*)d_in[3];
    const float* ad1 = (const float*)d_in[4];
    const float* b1  = (const float*)d_in[5];
    const float* W2  = (const float*)d_in[6];
    const float* as2 = (const float*)d_in[7];
    const float* ad2 = (const float*)d_in[8];
    const float* b2  = (const float*)d_in[9];
    float* out = (float*)d_out;

    char* p = (char*)d_ws;
    auto alloc = [&](size_t bytes) { char* r = p; p += (bytes + 255) & ~size_t(255); return (void*)r; };
    int* bcur  = (int*)alloc(sizeof(int) * NB);
    int* offB  = (int*)alloc(sizeof(int) * N);
    int* offE  = (int*)alloc(sizeof(int) * N);
    int* perm  = (int*)alloc(sizeof(int) * N);
    unsigned short* srcs = (unsigned short*)alloc(sizeof(unsigned short) * (size_t)NB * CAP);
    __half* H16a  = (__half*)alloc(sizeof(__half) * (size_t)N * NF);
    __half* H16b  = (__half*)alloc(sizeof(__half) * (size_t)N * NF);
    __half* Wpk1  = (__half*)alloc(sizeof(__half) * NF * NF);
    __half* Wpk2  = (__half*)alloc(sizeof(__half) * NF * NF);
    float* AS1 = (float*)alloc(sizeof(float) * N);
    float* AD1 = (float*)alloc(sizeof(float) * N);
    float* AS2 = (float*)alloc(sizeof(float) * N);
    float* AD2 = (float*)alloc(sizeof(float) * N);
    float* w2as = (float*)alloc(sizeof(float) * NF);
    float* w2ad = (float*)alloc(sizeof(float) * NF);
    int* packed = (int*)alloc(sizeof(int) * (size_t)NB * CAP);

    hipMemsetAsync(bcur, 0, sizeof(int) * NB, stream);
    k_scatter_packw<<<NBLK + PACKW_BLKS + 1, 1024, 0, stream>>>(
        ei, bcur, packed, W1, W2, Wpk1, Wpk2, as2, ad2, w2as, w2ad);
    k_csr_gemm1<<<2 * GEMM1_BLKS, 512, 0, stream>>>(packed, bcur, offB, offE, srcs, perm,
                                                    x, Wpk1, as1, ad1, H16a, AS1, AD1);
    k_agg1_gemm2<<<N / 16, 1024, 0, stream>>>(H16a, AS1, AD1, offB, offE, srcs, perm,
                                              b1, Wpk2, w2as, w2ad, H16b, AS2, AD2);
    k_aggregate2<<<N / 4, 256, 0, stream>>>(H16b, AS2, AD2, offB, offE, srcs, perm, b2, out);
}

// Round 20
// 173.072 us; speedup vs baseline: 2.4452x; 1.1034x over previous
//
#include <hip/hip_runtime.h>
#include <hip/hip_fp16.h>

constexpr int N  = 50000;
constexpr int E  = 1600000;                 // self-loops handled analytically
constexpr int NF = 128;
constexpr int BSH = 128;                    // dsts per bucket
constexpr int NB = (N + BSH - 1) / BSH;     // 391 buckets
constexpr int CAP = 8192;                   // slots per bucket (mean ~4094, sigma 64)
constexpr int EPB  = 8192;                  // edges per block (binscatter)
constexpr int NBLK = (E + EPB - 1) / EPB;   // 196
constexpr int PACKW_BLKS = (2 * NF * NF + 1023) / 1024;  // 32
constexpr int GEMM1_BLKS = (N + 127) / 128; // 391
constexpr int SCAPW = 128;                  // per-wave edge stash in aggregate

typedef _Float16 half8 __attribute__((ext_vector_type(8)));
typedef float    f32x4 __attribute__((ext_vector_type(4)));

// ---------------- fused binscatter + weight packing + w2 projections ----------------
__global__ __launch_bounds__(1024) void k_scatter_packw(
    const int* __restrict__ ei, int* __restrict__ bcur, int* __restrict__ packed,
    const float* __restrict__ W1, const float* __restrict__ W2,
    __half* __restrict__ P1, __half* __restrict__ P2,
    const float* __restrict__ as2, const float* __restrict__ ad2,
    float* __restrict__ w2as, float* __restrict__ w2ad) {
    int t = threadIdx.x;
    if (blockIdx.x == NBLK + PACKW_BLKS) {  // ---- w2 projection path ----
        if (t < NF) {
            float ps = 0.f, pd = 0.f;
            for (int j = 0; j < NF; ++j) {
                float w = W2[t * NF + j];
                ps = fmaf(w, as2[j], ps);
                pd = fmaf(w, ad2[j], pd);
            }
            w2as[t] = ps; w2ad[t] = pd;
        }
        return;
    }
    if (blockIdx.x >= NBLK) {               // ---- packw path ----
        int tid = (blockIdx.x - NBLK) * 1024 + t;
        if (tid >= 2 * NF * NF) return;
        int which = tid >> 14;
        int id = tid & (NF * NF - 1);
        int k = id >> 7, n = id & 127;
        const float* W = which ? W2 : W1;
        __half* P = which ? P2 : P1;
        int ks = k >> 5, r = k & 31, ct = n >> 4;
        int lane = ((r >> 3) << 4) | (n & 15);
        int j = r & 7;
        P[((ks * 8 + ct) * 64 + lane) * 8 + j] = __float2half_rn(W[k * NF + n]);
        return;
    }
    // ---- binscatter path (real edges only; self-loops analytic) ----
    __shared__ int h[NB], lcur[NB], garr[NB];
    for (int i = t; i < NB; i += 1024) h[i] = 0;
    __syncthreads();
    int base = blockIdx.x * EPB;
    int pk[EPB / 1024];
    int bk[EPB / 1024];
#pragma unroll
    for (int k = 0; k < EPB / 1024; ++k) {
        int i = base + k * 1024 + t;
        if (i < E) {
            int s = ei[i], d = ei[E + i];
            bk[k] = d >> 7;
            pk[k] = s | ((d & (BSH - 1)) << 16);
            atomicAdd(&h[bk[k]], 1);
        } else bk[k] = -1;
    }
    __syncthreads();
    for (int i = t; i < NB; i += 1024) {
        lcur[i] = 0;
        garr[i] = i * CAP + (h[i] ? atomicAdd(&bcur[i], h[i]) : 0);
    }
    __syncthreads();
#pragma unroll
    for (int k = 0; k < EPB / 1024; ++k) {
        if (bk[k] >= 0) {
            int p = garr[bk[k]] + atomicAdd(&lcur[bk[k]], 1);
            packed[p] = pk[k];
        }
    }
}

// ---------------- shared GEMM wave body (16 rows x 128 cols) ----------------
template <typename AT>
__device__ __forceinline__ void gemm_rows16(
    const AT* __restrict__ A, const half8* __restrict__ BP,
    const float* __restrict__ asv, const float* __restrict__ adv,
    __half* __restrict__ H16, float* __restrict__ AS, float* __restrict__ AD,
    int base, int lane) {
    int row_a = base + (lane & 15);
    if (row_a >= N) row_a = N - 1;
    const AT* Arow = A + (size_t)row_a * NF;

    f32x4 acc[8] = {};
#pragma unroll
    for (int ks = 0; ks < 4; ++ks) {
        int eo = (ks * 4 + (lane >> 4)) * 8;
        half8 a;
        if constexpr (sizeof(AT) == 4) {
            float4 u = *(const float4*)(Arow + eo);
            float4 v = *(const float4*)(Arow + eo + 4);
            a[0] = (_Float16)u.x; a[1] = (_Float16)u.y; a[2] = (_Float16)u.z; a[3] = (_Float16)u.w;
            a[4] = (_Float16)v.x; a[5] = (_Float16)v.y; a[6] = (_Float16)v.z; a[7] = (_Float16)v.w;
        } else {
            a = ((const half8*)Arow)[ks * 4 + (lane >> 4)];
        }
#pragma unroll
        for (int ct = 0; ct < 8; ++ct) {
            half8 b = BP[(ks * 8 + ct) * 64 + lane];
            acc[ct] = __builtin_amdgcn_mfma_f32_16x16x32_f16(a, b, acc[ct], 0, 0, 0);
        }
    }

    int colb = lane & 15;
    int rowq = base + (lane >> 4) * 4;
    float ps[4] = {0.f, 0.f, 0.f, 0.f};
    float pd[4] = {0.f, 0.f, 0.f, 0.f};
#pragma unroll
    for (int ct = 0; ct < 8; ++ct) {
        int col = ct * 16 + colb;
        float av = asv[col], dv = adv[col];
#pragma unroll
        for (int r = 0; r < 4; ++r) {
            float hv = acc[ct][r];
            if (rowq + r < N) H16[(size_t)(rowq + r) * NF + col] = __float2half_rn(hv);
            ps[r] = fmaf(hv, av, ps[r]);
            pd[r] = fmaf(hv, dv, pd[r]);
        }
    }
#pragma unroll
    for (int r = 0; r < 4; ++r) {
#pragma unroll
        for (int o = 1; o <= 8; o <<= 1) {
            ps[r] += __shfl_xor(ps[r], o);
            pd[r] += __shfl_xor(pd[r], o);
        }
    }
    if (colb == 0) {
#pragma unroll
        for (int r = 0; r < 4; ++r) {
            if (rowq + r < N) { AS[rowq + r] = ps[r]; AD[rowq + r] = pd[r]; }
        }
    }
}

// ---------------- fused k_csr + layer-1 GEMM (even/odd split) ----------------
__global__ __launch_bounds__(512) void k_csr_gemm1(
    const int* __restrict__ packed, const int* __restrict__ bcur,
    int* __restrict__ offB, int* __restrict__ offE, unsigned short* __restrict__ srcs,
    const float* __restrict__ X, const __half* __restrict__ Wpk,
    const float* __restrict__ asv, const float* __restrict__ adv,
    __half* __restrict__ H16, float* __restrict__ AS, float* __restrict__ AD) {
    int t = threadIdx.x;
    if ((blockIdx.x & 1) == 0) {            // ---- GEMM1 path ----
        int blk = blockIdx.x >> 1;
        int wave = t >> 6, lane = t & 63;
        int base = blk * 128 + wave * 16;
        gemm_rows16<float>(X, (const half8*)Wpk, asv, adv, H16, AS, AD, base, lane);
        return;
    }
    // ---- csr path ----
    int b = blockIdx.x >> 1;
    int s0 = b * CAP;
    int n = bcur[b];
    __shared__ int buf[CAP];
    __shared__ int h[BSH], bas[BSH], lcur[BSH];
    for (int i = t; i < n; i += 512) buf[i] = packed[s0 + i];
    if (t < BSH) { h[t] = 0; lcur[t] = 0; }
    __syncthreads();
    for (int i = t; i < n; i += 512)
        atomicAdd(&h[(buf[i] >> 16) & (BSH - 1)], 1);
    __syncthreads();
    if (t < 64) {                           // one wave scans 128 bins, 2 per lane
        int v0 = h[2 * t], v1 = h[2 * t + 1];
        int pair = v0 + v1, x = pair;
#pragma unroll
        for (int o = 1; o < 64; o <<= 1) {
            int y = __shfl_up(x, o);
            if (t >= o) x += y;
        }
        int e0 = s0 + x - pair;
        int e1 = e0 + v0;
        bas[2 * t] = e0; bas[2 * t + 1] = e1;
        int d = b * BSH + 2 * t;
        if (d < N)     { offB[d] = e0;     offE[d] = e1; }
        if (d + 1 < N) { offB[d + 1] = e1; offE[d + 1] = s0 + x; }
    }
    __syncthreads();
    for (int i = t; i < n; i += 512) {
        int p = buf[i];
        int dl = (p >> 16) & (BSH - 1);
        int pos = bas[dl] + atomicAdd(&lcur[dl], 1);
        srcs[pos] = (unsigned short)(p & 0xFFFF);
    }
}

// ---------------- aggregate-1 fused with layer-2 GEMM (16-wave layout) ----------------
__global__ __launch_bounds__(1024) void k_agg1_gemm2(
    const __half* __restrict__ H16in, const float* __restrict__ AS, const float* __restrict__ AD,
    const int* __restrict__ offB, const int* __restrict__ offE,
    const unsigned short* __restrict__ srcs,
    const float* __restrict__ b1, const __half* __restrict__ Wpk2,
    const float* __restrict__ w2as, const float* __restrict__ w2ad,
    __half* __restrict__ H16out, float* __restrict__ AS2, float* __restrict__ AD2) {
    int wave = threadIdx.x >> 6, lane = threadIdx.x & 63;
    int d = blockIdx.x * 16 + wave;         // N % 16 == 0

    __shared__ float ssv[16][SCAPW];
    __shared__ unsigned short ssrc[16][SCAPW];
    __shared__ __half Y[16][136];

    int beg = offB[d], deg = offE[d] - beg;
    float ad = AD[d];

    // pass 1: one exp per edge, stash, wave-reduce denominator
    float ls = 0.f;
    for (int i = lane; i < deg; i += 64) {
        int s = srcs[beg + i];
        float sv = AS[s] + ad;
        sv = (sv > 0.f) ? sv : 0.2f * sv;
        float e = __expf(fminf(sv, 60.f));
        if (i < SCAPW) { ssv[wave][i] = e; ssrc[wave][i] = (unsigned short)s; }
        ls += e;
    }
#pragma unroll
    for (int o = 1; o <= 32; o <<= 1) ls += __shfl_xor(ls, o);
    // analytic self-loop
    float slv = AS[d] + ad;
    slv = (slv > 0.f) ? slv : 0.2f * slv;
    float es = __expf(fminf(slv, 60.f));
    ls += es;
    float inv = 1.f / (ls + 1e-16f);

    // pass 2: gather-accumulate, 2x unrolled
    int tx = lane & 15, u = lane >> 4;
    float acc[8] = {0.f, 0.f, 0.f, 0.f, 0.f, 0.f, 0.f, 0.f};
    for (int j0 = 0; j0 < deg; j0 += 8) {
        int i0 = j0 + u, i1 = j0 + 4 + u;
        float e0 = 0.f, e1 = 0.f;
        int s0 = 0, s1 = 0;
        bool v0 = i0 < deg, v1 = i1 < deg;
        if (v0) {
            if (i0 < SCAPW) { e0 = ssv[wave][i0]; s0 = ssrc[wave][i0]; }
            else {
                s0 = srcs[beg + i0];
                float sv = AS[s0] + ad;
                sv = (sv > 0.f) ? sv : 0.2f * sv;
                e0 = __expf(fminf(sv, 60.f));
            }
        }
        if (v1) {
            if (i1 < SCAPW) { e1 = ssv[wave][i1]; s1 = ssrc[wave][i1]; }
            else {
                s1 = srcs[beg + i1];
                float sv = AS[s1] + ad;
                sv = (sv > 0.f) ? sv : 0.2f * sv;
                e1 = __expf(fminf(sv, 60.f));
            }
        }
        union { float4 f; __half2 h[4]; } va, vb;
        if (v0) va.f = *reinterpret_cast<const float4*>(H16in + (size_t)s0 * NF + tx * 8);
        if (v1) vb.f = *reinterpret_cast<const float4*>(H16in + (size_t)s1 * NF + tx * 8);
        if (v0) {
            float2 f0 = __half22float2(va.h[0]);
            float2 f1 = __half22float2(va.h[1]);
            float2 f2 = __half22float2(va.h[2]);
            float2 f3 = __half22float2(va.h[3]);
            acc[0] = fmaf(e0, f0.x, acc[0]); acc[1] = fmaf(e0, f0.y, acc[1]);
            acc[2] = fmaf(e0, f1.x, acc[2]); acc[3] = fmaf(e0, f1.y, acc[3]);
            acc[4] = fmaf(e0, f2.x, acc[4]); acc[5] = fmaf(e0, f2.y, acc[5]);
            acc[6] = fmaf(e0, f3.x, acc[6]); acc[7] = fmaf(e0, f3.y, acc[7]);
        }
        if (v1) {
            float2 f0 = __half22float2(vb.h[0]);
            float2 f1 = __half22float2(vb.h[1]);
            float2 f2 = __half22float2(vb.h[2]);
            float2 f3 = __half22float2(vb.h[3]);
            acc[0] = fmaf(e1, f0.x, acc[0]); acc[1] = fmaf(e1, f0.y, acc[1]);
            acc[2] = fmaf(e1, f1.x, acc[2]); acc[3] = fmaf(e1, f1.y, acc[3]);
            acc[4] = fmaf(e1, f2.x, acc[4]); acc[5] = fmaf(e1, f2.y, acc[5]);
            acc[6] = fmaf(e1, f3.x, acc[6]); acc[7] = fmaf(e1, f3.y, acc[7]);
        }
    }
#pragma unroll
    for (int o = 16; o <= 32; o <<= 1) {
#pragma unroll
        for (int i = 0; i < 8; ++i) acc[i] += __shfl_xor(acc[i], o);
    }
    // self contribution
    {
        union { float4 f; __half2 h[4]; } vs;
        vs.f = *reinterpret_cast<const float4*>(H16in + (size_t)d * NF + tx * 8);
        float2 f0 = __half22float2(vs.h[0]);
        float2 f1 = __half22float2(vs.h[1]);
        float2 f2 = __half22float2(vs.h[2]);
        float2 f3 = __half22float2(vs.h[3]);
        acc[0] = fmaf(es, f0.x, acc[0]); acc[1] = fmaf(es, f0.y, acc[1]);
        acc[2] = fmaf(es, f1.x, acc[2]); acc[3] = fmaf(es, f1.y, acc[3]);
        acc[4] = fmaf(es, f2.x, acc[4]); acc[5] = fmaf(es, f2.y, acc[5]);
        acc[6] = fmaf(es, f3.x, acc[6]); acc[7] = fmaf(es, f3.y, acc[7]);
    }
    // epilogue math: y = leaky(acc*inv + b1); alpha-2 via precomputed projections
    float y[8];
    float ps = 0.f, pd = 0.f;
#pragma unroll
    for (int i = 0; i < 8; ++i) {
        float v = acc[i] * inv + b1[tx * 8 + i];
        v = (v < 0.f) ? 0.01f * v : v;
        y[i] = v;
        ps = fmaf(v, w2as[tx * 8 + i], ps);
        pd = fmaf(v, w2ad[tx * 8 + i], pd);
    }
#pragma unroll
    for (int o = 1; o <= 8; o <<= 1) { ps += __shfl_xor(ps, o); pd += __shfl_xor(pd, o); }
    if (lane == 0) { AS2[d] = ps; AD2[d] = pd; }
    if (lane < 16) {
        half8 hv;
#pragma unroll
        for (int i = 0; i < 8; ++i) hv[i] = (_Float16)y[i];
        *(half8*)(&Y[wave][tx * 8]) = hv;
    }
    __syncthreads();
    // epilogue GEMM: waves 0-7 each compute one 16-col tile of Y(16x128)@W2
    if (wave < 8) {
        const half8* BP = (const half8*)Wpk2;
        f32x4 c4 = {};
#pragma unroll
        for (int ks = 0; ks < 4; ++ks) {
            half8 a = *(const half8*)(&Y[lane & 15][ks * 32 + (lane >> 4) * 8]);
            half8 b = BP[(ks * 8 + wave) * 64 + lane];
            c4 = __builtin_amdgcn_mfma_f32_16x16x32_f16(a, b, c4, 0, 0, 0);
        }
        int base = blockIdx.x * 16;
        int colb = lane & 15;
        int rowq = (lane >> 4) * 4;
#pragma unroll
        for (int r = 0; r < 4; ++r)
            H16out[(size_t)(base + rowq + r) * NF + wave * 16 + colb] = __float2half_rn(c4[r]);
    }
}

// ---------------- layer-2 aggregate (wave-per-dst, fp32 out) ----------------
__global__ __launch_bounds__(256) void k_aggregate2(
    const __half* __restrict__ H16, const float* __restrict__ AS, const float* __restrict__ AD,
    const int* __restrict__ offB, const int* __restrict__ offE,
    const unsigned short* __restrict__ srcs,
    const float* __restrict__ bias, float* __restrict__ OUT) {
    int wave = threadIdx.x >> 6, lane = threadIdx.x & 63;
    int d = blockIdx.x * 4 + wave;

    __shared__ float ssv[4][SCAPW];
    __shared__ unsigned short ssrc[4][SCAPW];

    int beg = offB[d], deg = offE[d] - beg;
    float ad = AD[d];

    float ls = 0.f;
    for (int i = lane; i < deg; i += 64) {
        int s = srcs[beg + i];
        float sv = AS[s] + ad;
        sv = (sv > 0.f) ? sv : 0.2f * sv;
        float e = __expf(fminf(sv, 60.f));
        if (i < SCAPW) { ssv[wave][i] = e; ssrc[wave][i] = (unsigned short)s; }
        ls += e;
    }
#pragma unroll
    for (int o = 1; o <= 32; o <<= 1) ls += __shfl_xor(ls, o);
    float slv = AS[d] + ad;
    slv = (slv > 0.f) ? slv : 0.2f * slv;
    float es = __expf(fminf(slv, 60.f));
    ls += es;
    float inv = 1.f / (ls + 1e-16f);

    int tx = lane & 15, u = lane >> 4;
    float acc[8] = {0.f, 0.f, 0.f, 0.f, 0.f, 0.f, 0.f, 0.f};
    for (int j0 = 0; j0 < deg; j0 += 8) {
        int i0 = j0 + u, i1 = j0 + 4 + u;
        float e0 = 0.f, e1 = 0.f;
        int s0 = 0, s1 = 0;
        bool v0 = i0 < deg, v1 = i1 < deg;
        if (v0) {
            if (i0 < SCAPW) { e0 = ssv[wave][i0]; s0 = ssrc[wave][i0]; }
            else {
                s0 = srcs[beg + i0];
                float sv = AS[s0] + ad;
                sv = (sv > 0.f) ? sv : 0.2f * sv;
                e0 = __expf(fminf(sv, 60.f));
            }
        }
        if (v1) {
            if (i1 < SCAPW) { e1 = ssv[wave][i1]; s1 = ssrc[wave][i1]; }
            else {
                s1 = srcs[beg + i1];
                float sv = AS[s1] + ad;
                sv = (sv > 0.f) ? sv : 0.2f * sv;
                e1 = __expf(fminf(sv, 60.f));
            }
        }
        union { float4 f; __half2 h[4]; } va, vb;
        if (v0) va.f = *reinterpret_cast<const float4*>(H16 + (size_t)s0 * NF + tx * 8);
        if (v1) vb.f = *reinterpret_cast<const float4*>(H16 + (size_t)s1 * NF + tx * 8);
        if (v0) {
            float2 f0 = __half22float2(va.h[0]);
            float2 f1 = __half22float2(va.h[1]);
            float2 f2 = __half22float2(va.h[2]);
            float2 f3 = __half22float2(va.h[3]);
            acc[0] = fmaf(e0, f0.x, acc[0]); acc[1] = fmaf(e0, f0.y, acc[1]);
            acc[2] = fmaf(e0, f1.x, acc[2]); acc[3] = fmaf(e0, f1.y, acc[3]);
            acc[4] = fmaf(e0, f2.x, acc[4]); acc[5] = fmaf(e0, f2.y, acc[5]);
            acc[6] = fmaf(e0, f3.x, acc[6]); acc[7] = fmaf(e0, f3.y, acc[7]);
        }
        if (v1) {
            float2 f0 = __half22float2(vb.h[0]);
            float2 f1 = __half22float2(vb.h[1]);
            float2 f2 = __half22float2(vb.h[2]);
            float2 f3 = __half22float2(vb.h[3]);
            acc[0] = fmaf(e1, f0.x, acc[0]); acc[1] = fmaf(e1, f0.y, acc[1]);
            acc[2] = fmaf(e1, f1.x, acc[2]); acc[3] = fmaf(e1, f1.y, acc[3]);
            acc[4] = fmaf(e1, f2.x, acc[4]); acc[5] = fmaf(e1, f2.y, acc[5]);
            acc[6] = fmaf(e1, f3.x, acc[6]); acc[7] = fmaf(e1, f3.y, acc[7]);
        }
    }
#pragma unroll
    for (int o = 16; o <= 32; o <<= 1) {
#pragma unroll
        for (int i = 0; i < 8; ++i) acc[i] += __shfl_xor(acc[i], o);
    }
    {
        union { float4 f; __half2 h[4]; } vs;
        vs.f = *reinterpret_cast<const float4*>(H16 + (size_t)d * NF + tx * 8);
        float2 f0 = __half22float2(vs.h[0]);
        float2 f1 = __half22float2(vs.h[1]);
        float2 f2 = __half22float2(vs.h[2]);
        float2 f3 = __half22float2(vs.h[3]);
        acc[0] = fmaf(es, f0.x, acc[0]); acc[1] = fmaf(es, f0.y, acc[1]);
        acc[2] = fmaf(es, f1.x, acc[2]); acc[3] = fmaf(es, f1.y, acc[3]);
        acc[4] = fmaf(es, f2.x, acc[4]); acc[5] = fmaf(es, f2.y, acc[5]);
        acc[6] = fmaf(es, f3.x, acc[6]); acc[7] = fmaf(es, f3.y, acc[7]);
    }
    if (lane < 16) {
        float o8[8];
#pragma unroll
        for (int i = 0; i < 8; ++i) o8[i] = acc[i] * inv + bias[tx * 8 + i];
        float4 w0 = {o8[0], o8[1], o8[2], o8[3]};
        float4 w1 = {o8[4], o8[5], o8[6], o8[7]};
        ((float4*)OUT)[(size_t)d * 32 + tx * 2]     = w0;
        ((float4*)OUT)[(size_t)d * 32 + tx * 2 + 1] = w1;
    }
}

extern "C" void kernel_launch(void* const* d_in, const int* in_sizes, int n_in,
                              void* d_out, int out_size, void* d_ws, size_t ws_size,
                              hipStream_t stream) {
    const float* x   = (const float*)d_in[0];
    const int*   ei  = (const int*)d_in[1];
    const float* W1  = (const float*)d_in[2];
    const float* as1 = (const float*)d_in[3];
    const float* ad1 = (const float*)d_in[4];
    const float* b1  = (const float*)d_in[5];
    const float* W2  = (const float*)d_in[6];
    const float* as2 = (const float*)d_in[7];
    const float* ad2 = (const float*)d_in[8];
    const float* b2  = (const float*)d_in[9];
    float* out = (float*)d_out;

    char* p = (char*)d_ws;
    auto alloc = [&](size_t bytes) { char* r = p; p += (bytes + 255) & ~size_t(255); return (void*)r; };
    int* bcur  = (int*)alloc(sizeof(int) * NB);
    int* offB  = (int*)alloc(sizeof(int) * N);
    int* offE  = (int*)alloc(sizeof(int) * N);
    unsigned short* srcs = (unsigned short*)alloc(sizeof(unsigned short) * (size_t)NB * CAP);
    __half* H16a  = (__half*)alloc(sizeof(__half) * (size_t)N * NF);
    __half* H16b  = (__half*)alloc(sizeof(__half) * (size_t)N * NF);
    __half* Wpk1  = (__half*)alloc(sizeof(__half) * NF * NF);
    __half* Wpk2  = (__half*)alloc(sizeof(__half) * NF * NF);
    float* AS1 = (float*)alloc(sizeof(float) * N);
    float* AD1 = (float*)alloc(sizeof(float) * N);
    float* AS2 = (float*)alloc(sizeof(float) * N);
    float* AD2 = (float*)alloc(sizeof(float) * N);
    float* w2as = (float*)alloc(sizeof(float) * NF);
    float* w2ad = (float*)alloc(sizeof(float) * NF);
    int* packed = (int*)alloc(sizeof(int) * (size_t)NB * CAP);

    hipMemsetAsync(bcur, 0, sizeof(int) * NB, stream);
    k_scatter_packw<<<NBLK + PACKW_BLKS + 1, 1024, 0, stream>>>(
        ei, bcur, packed, W1, W2, Wpk1, Wpk2, as2, ad2, w2as, w2ad);
    k_csr_gemm1<<<2 * GEMM1_BLKS, 512, 0, stream>>>(packed, bcur, offB, offE, srcs,
                                                    x, Wpk1, as1, ad1, H16a, AS1, AD1);
    k_agg1_gemm2<<<N / 16, 1024, 0, stream>>>(H16a, AS1, AD1, offB, offE, srcs,
                                              b1, Wpk2, w2as, w2ad, H16b, AS2, AD2);
    k_aggregate2<<<N / 4, 256, 0, stream>>>(H16b, AS2, AD2, offB, offE, srcs, b2, out);
}